// Round 1
// 25002.850 us; speedup vs baseline: 1.0581x; 1.0581x over previous
//
#include <hip/hip_runtime.h>
#include <math.h>

#define NCH 2048
#define NT 256

typedef _Float16 h8 __attribute__((ext_vector_type(8)));
typedef float f4 __attribute__((ext_vector_type(4)));

#define MFMA(d, a, b) d = __builtin_amdgcn_mfma_f32_16x16x32_f16(a, b, d, 0, 0, 0)

// Static device scratch (avoids any assumption about ws_size).
__device__ float2 g_X[(size_t)NCH * 128 * 65];     // 136 MB
__device__ float2 g_Y[(size_t)NCH * 128 * 65];     // 136 MB
__device__ float2 g_ring[(size_t)NCH * 57 * 132];  // 123 MB
__device__ int    g_owner[64 * 33];
// Precomputed twiddle-fragment matrices, fp16 hi/lo (lo pre-scaled x2048).
// Per-res slot = 114688 fp16: [Wtt 8x8192][Wsyn 2x16384][Wana 2x8192]
__device__ _Float16 g_W[(size_t)56 * 114688];      // 12.8 MB

__device__ __forceinline__ float gelu_exact(float v) {
  return 0.5f * v * (1.0f + erff(v * 0.70710678118654752440f));
}

// incremental complex rotation: (co,si) *= (cs,ss)
#define ROT(co, si, cs, ss) { float _n = co * cs - si * ss; si = si * cs + co * ss; co = _n; }

// ---------------------------------------------------------------------------
// R1: row-wise DFT along v: Y[ch,u,k2] = sum_v x[ch,u,v] e^{-2pi i k2 v/128}
// ---------------------------------------------------------------------------
__global__ __launch_bounds__(NT) void r1_kernel(const float* __restrict__ x) {
  __shared__ float xb[16 * 128];
  __shared__ float tw[256];
  int ch = blockIdx.x >> 3, grp = blockIdx.x & 7;
  int tid = threadIdx.x;
  for (int t = tid; t < 128; t += NT) {
    float s, co; sincosf(6.283185307179586f * (float)t / 128.0f, &s, &co);
    tw[2 * t] = co; tw[2 * t + 1] = s;
  }
  const float* xp = x + ((size_t)ch * 128 + grp * 16) * 128;
  for (int i = tid; i < 16 * 128; i += NT) xb[i] = xp[i];
  __syncthreads();
  for (int idx = tid; idx < 16 * 65; idx += NT) {
    int u = idx / 65, k2 = idx - 65 * u;
    const float* row = xb + u * 128;
    float cb = tw[2 * k2], sbr = tw[2 * k2 + 1];
    int t2 = (2 * k2) & 127;
    float cs = tw[2 * t2], ss = tw[2 * t2 + 1];
    float ca = 1.f, sa = 0.f;
    float ar = 0.f, ai = 0.f;
    for (int v = 0; v < 128; v += 2) {
      float x0 = row[v], x1 = row[v + 1];
      ar += x0 * ca; ai -= x0 * sa;
      ar += x1 * cb; ai -= x1 * sbr;
      ROT(ca, sa, cs, ss); ROT(cb, sbr, cs, ss);
    }
    g_Y[((size_t)ch * 128 + grp * 16 + u) * 65 + k2] = make_float2(ar, ai);
  }
}

// ---------------------------------------------------------------------------
// R2: col-wise DFT along u + 1/16384 norm. Pairs k1 and k1+64 via (-1)^u.
// ---------------------------------------------------------------------------
__global__ __launch_bounds__(NT) void r2_kernel() {
  __shared__ float2 yb[128 * 8];
  __shared__ float tw[256];
  int ch = blockIdx.x / 9, cg = blockIdx.x - 9 * ch;
  int c0 = cg * 8, nc = min(8, 65 - c0);
  int tid = threadIdx.x;
  for (int t = tid; t < 128; t += NT) {
    float s, co; sincosf(6.283185307179586f * (float)t / 128.0f, &s, &co);
    tw[2 * t] = co; tw[2 * t + 1] = s;
  }
  for (int i = tid; i < 128 * nc; i += NT) {
    int u = i / nc, j = i - nc * u;
    yb[u * 8 + j] = g_Y[((size_t)ch * 128 + u) * 65 + c0 + j];
  }
  __syncthreads();
  const float inv = 1.0f / 16384.0f;
  for (int idx = tid; idx < 64 * nc; idx += NT) {
    int k1 = idx & 63, j = idx >> 6;
    float cb = tw[2 * k1], sbr = tw[2 * k1 + 1];
    int t2 = (2 * k1) & 127;
    float cs = tw[2 * t2], ss = tw[2 * t2 + 1];
    float ca = 1.f, sa = 0.f;
    float ar = 0.f, ai = 0.f, br = 0.f, bi = 0.f;
    for (int u = 0; u < 128; u += 2) {
      float2 e = yb[u * 8 + j];
      float pr = e.x * ca + e.y * sa, pi2 = e.y * ca - e.x * sa;
      ar += pr; ai += pi2; br += pr; bi += pi2;
      e = yb[(u + 1) * 8 + j];
      float pr2 = e.x * cb + e.y * sbr, pi3 = e.y * cb - e.x * sbr;
      ar += pr2; ai += pi3; br -= pr2; bi -= pi3;
      ROT(ca, sa, cs, ss); ROT(cb, sbr, cs, ss);
    }
    g_X[((size_t)ch * 128 + k1) * 65 + c0 + j]      = make_float2(ar * inv, ai * inv);
    g_X[((size_t)ch * 128 + k1 + 64) * 65 + c0 + j] = make_float2(br * inv, bi * inv);
  }
}

// ---------------------------------------------------------------------------
// Owner map (reference's sequential overwrite order).
// ---------------------------------------------------------------------------
__device__ __forceinline__ int owner_slot(int rr, int k2, int ri) {
  if (ri == 0) {
    if (k2 <= 4) {
      if (rr <= 3) return rr * 5 + k2;
      if (rr >= 60) return (rr - 56) * 5 + k2;
    }
    return -1;
  }
  int res = 16 + 2 * ri, c = res / 2, h = c / 2;
  if (c & 1) {
    if (rr == h && k2 <= h) return k2;
    if (rr == 64 - h && k2 <= h) return (h + 1) + k2;
    if (k2 == h) {
      if (rr <= h) return 2 * (h + 1) + rr;
      if (rr >= 64 - h) return 2 * (h + 1) + (rr - 64 + c);
    }
  } else {
    if (rr == 64 - h && k2 <= h) return (h + 1) + k2;
    if (k2 == h) {
      if (rr >= 64 - h) return 2 * (h + 1) + (rr - 64 + c);
      if (rr < h) return 2 * (h + 1) + rr;
    }
  }
  return -1;
}

__global__ __launch_bounds__(NT) void owner_kernel() {
  int cell = blockIdx.x * NT + threadIdx.x;
  if (cell >= 64 * 33) return;
  int rr = cell / 33, k2 = cell - 33 * (cell / 33);
  int result = -1;
  for (int ri = 56; ri >= 0 && result < 0; ri--) {
    int slot = owner_slot(rr, k2, ri);
    if (slot >= 0) result = ri * 256 + slot;
  }
  g_owner[cell] = result;
}

// ---------------------------------------------------------------------------
// Twiddle-fragment precompute: per res r = 16..126 step 2 (ri = (r-16)/2).
// All matrices stored as lane-packed 16x32 MFMA fragments (512 fp16/tile):
//   A-type (Wtt):  value(row = mt*16 + (l&15), k = kt*32 + (l>>4)*8 + e)
//   B-type (Wsyn/Wana): value(col = nt*16 + (l&15), k = kt*32 + (l>>4)*8 + e)
// hi/lo split: lo = (v - (f32)(f16)v) * 2048  (avoids f16 denormal loss).
// ---------------------------------------------------------------------------
__global__ __launch_bounds__(256) void wprep_kernel() {
  int r = 16 + 2 * blockIdx.x;
  int c = r >> 1, cp1 = c + 1, c2 = (c >> 1) + 1;
  int KTT = 32 * ((2 * c + 31) >> 5);        // K for TTmm (2c) and ana (r)
  int NTP = 16 * ((cp1 + 15) >> 4);          // TTmm N-pad
  int KSY = 2 * NTP;                         // syn K (2*cp1 padded)
  int NSY = KTT;                             // syn N-pad (v-dim = 2c padded)
  int NAN_ = 16 * ((2 * c2 + 15) >> 4);      // ana N-pad (re/im interleaved)
  int MT = (c + 15) >> 4;                    // M-chunks per parity
  int ktt = KTT >> 5, kts = KSY >> 5;
  _Float16* W = g_W + (size_t)blockIdx.x * 114688;
  const float TP = 6.283185307179586f;
  float invr = 1.0f / (float)r;

  // ---- Wtt: s = par*4 + v*2 + h.  A1=(cos,-sin) -> re, A2=(sin,cos) -> im
  int tot = 8 * MT * ktt * 64;
  for (int fi = threadIdx.x; fi < tot; fi += 256) {
    int l = fi & 63, rest = fi >> 6;
    int kt = rest % ktt; rest /= ktt;
    int mt = rest % MT;  rest /= MT;
    int s = rest;
    int hh = s & 1, vv = (s >> 1) & 1, par = s >> 2;
    int i = mt * 16 + (l & 15);
    int u = 2 * i + par;
    int kb = kt * 32 + (l >> 4) * 8;
    h8 o;
    for (int e = 0; e < 8; e++) {
      int k = kb + e, kk = k >> 1, im = k & 1;
      float val = 0.f;
      if (i < c && kk < c) {
        int tm = (u * kk) % r;
        float sn, cs; sincosf(TP * (float)tm * invr, &sn, &cs);
        val = (vv == 0) ? (im ? -sn : cs) : (im ? cs : sn);
      }
      if (hh) { float hi = (float)(_Float16)val; val = (val - hi) * 2048.f; }
      o[e] = (_Float16)val;
    }
    *(h8*)(W + s * 8192 + (mt * ktt + kt) * 512 + l * 8) = o;
  }
  // ---- Wsyn (B-type): k-interleave (2k2)=alpha*cos, (2k2+1)=-alpha*sin
  int nts = NSY >> 4;
  tot = 2 * nts * kts * 64;
  for (int fi = threadIdx.x; fi < tot; fi += 256) {
    int l = fi & 63, rest = fi >> 6;
    int kt = rest % kts; rest /= kts;
    int nt = rest % nts; rest /= nts;
    int hh = rest;
    int v = nt * 16 + (l & 15);
    int kb = kt * 32 + (l >> 4) * 8;
    h8 o;
    for (int e = 0; e < 8; e++) {
      int k = kb + e, k2 = k >> 1, im = k & 1;
      float val = 0.f;
      if (k2 <= c) {
        int tm = (v * k2) % r;
        if (im) {
          if (k2 != 0 && k2 != c) val = -2.f * sinf(TP * (float)tm * invr);
        } else {
          float a = (k2 == 0 || k2 == c) ? 1.f : 2.f;
          val = a * cosf(TP * (float)tm * invr);
        }
      }
      if (hh) { float hi = (float)(_Float16)val; val = (val - hi) * 2048.f; }
      o[e] = (_Float16)val;
    }
    *(h8*)(W + 65536 + hh * 16384 + (nt * kts + kt) * 512 + l * 8) = o;
  }
  // ---- Wana (B-type): col n: even->cos(2pi k2 v/r), odd->-sin; k dim = v
  int nta = NAN_ >> 4;
  tot = 2 * nta * ktt * 64;
  for (int fi = threadIdx.x; fi < tot; fi += 256) {
    int l = fi & 63, rest = fi >> 6;
    int kt = rest % ktt; rest /= ktt;
    int nt = rest % nta; rest /= nta;
    int hh = rest;
    int n = nt * 16 + (l & 15);
    int k2 = n >> 1, im = n & 1;
    int kb = kt * 32 + (l >> 4) * 8;
    h8 o;
    for (int e = 0; e < 8; e++) {
      int v = kb + e;
      float val = 0.f;
      if (n < 2 * c2 && v < r) {
        int tm = (k2 * v) % r;
        val = im ? -sinf(TP * (float)tm * invr) : cosf(TP * (float)tm * invr);
      }
      if (hh) { float hi = (float)(_Float16)val; val = (val - hi) * 2048.f; }
      o[e] = (_Float16)val;
    }
    *(h8*)(W + 98304 + hh * 8192 + (nt * ktt + kt) * 512 + l * 8) = o;
  }
}

// ---------------------------------------------------------------------------
// Per-(channel,res) pipeline. Stage A (non-128) now runs on MFMA:
//   fe/fo parity fold -> TTmm -> syn+gelu -> ana  (fp16 split-3 emulation),
// with gacc / stage C / stage E still VALU.
// ---------------------------------------------------------------------------
template <int NTT_>
__global__ __launch_bounds__(NTT_) void pipe_kernel(const float* __restrict__ x, int res_hi) {
  const int NU = 8;
  int rorder = blockIdx.x / NCH;
  int ch = blockIdx.x - rorder * NCH;
  int r = res_hi - 2 * rorder;
  const int tid = threadIdx.x;
  const int lane = tid & 63;
  const int wid = tid >> 6;
  int c = r >> 1, cp1 = c + 1, m = c, c2 = (c >> 1) + 1, h = c >> 1;
  int rp2 = (m + 1) >> 1, rn2 = m >> 1;
  bool is128 = (r == 128);

  extern __shared__ float lds[];
  float* tw = lds;                               // 2r
  float* gdp = tw + 2 * r;                       // Gd (2*m*c2)
  float2* Gd = (float2*)gdp;
  float* tbp = gdp + 2 * m * c2;                 // TB (2*16*c2), 16 rows
  float2* TB = (float2*)tbp;
  float* big = (float*)(((size_t)(tbp + 2 * 16 * c2) + 15) & ~(size_t)15);

  for (int t = tid; t < r; t += NTT_) {
    float s, co; sincosf(6.283185307179586f * (float)t / (float)r, &s, &co);
    tw[2 * t] = co; tw[2 * t + 1] = s;
  }
  __syncthreads();

  const float2* Xc = g_X + (size_t)ch * (128 * 65);

  if (!is128) {
    const int KTT = 32 * ((2 * c + 31) >> 5);
    const int NTP = 16 * ((cp1 + 15) >> 4);
    const int KSY = 2 * NTP;
    const int NSY = KTT;
    const int NAN_ = 16 * ((2 * c2 + 15) >> 4);
    const int MT = (c + 15) >> 4;
    const int ktt = KTT >> 5, kts = KSY >> 5;
    const int sA = KTT + 8, sT = KSY + 8;        // padded fp16 row strides
    const _Float16* Wslot = g_W + (size_t)((r - 16) >> 1) * 114688;
    const _Float16* Wsy = Wslot + 65536;
    const _Float16* Wan = Wslot + 98304;
    _Float16* feHI = (_Float16*)big;
    _Float16* feLO = feHI + NTP * sA;
    _Float16* ttHI = feLO + NTP * sA;
    _Float16* ttLO = ttHI + 16 * sT;
    _Float16* sbHI = ttLO + 16 * sT;
    _Float16* sbLO = sbHI + 16 * sA;
    const int l15 = lane & 15;
    const int lk = (lane >> 4) << 3;
    const float LSC = 4.8828125e-4f;             // 1/2048
    bool first = true;
    int halfK = KTT >> 1;

    for (int par = 0; par < 2; par++) {
      // ---- build folded crop fe = pa +/- pb, transposed [j][2kk], hi/lo
      for (int idx = tid; idx < NTP * halfK; idx += NTT_) {
        int j = idx % NTP, kk = idx / NTP;
        float fx = 0.f, fy = 0.f;
        if (j < cp1 && kk < c) {
          float2 e1 = Xc[(size_t)kk * 65 + j];
          float2 e2 = Xc[(size_t)(128 - c + kk) * 65 + j];
          fx = par ? (e1.x - e2.x) : (e1.x + e2.x);
          fy = par ? (e1.y - e2.y) : (e1.y + e2.y);
        }
        int base = j * sA + 2 * kk;
        _Float16 xh = (_Float16)fx, yh = (_Float16)fy;
        feHI[base] = xh; feHI[base + 1] = yh;
        feLO[base] = (_Float16)((fx - (float)xh) * 2048.f);
        feLO[base + 1] = (_Float16)((fy - (float)yh) * 2048.f);
      }
      __syncthreads();

      for (int p = 0; p < MT; p++) {
        // ---- TTmm: TT[u][j] = sum_kk W[u][kk] * fe[kk][j]  (complex)
        for (int nt = wid; nt < (NTP >> 4); nt += NTT_ / 64) {
          f4 d1r = {0.f, 0.f, 0.f, 0.f}, d2r = d1r, d1i = d1r, d2i = d1r;
          const _Float16* pa1h = Wslot + (par * 4 + 0) * 8192 + (p * ktt) * 512 + lane * 8;
          const _Float16* pa1l = pa1h + 8192;
          const _Float16* pa2h = pa1h + 16384;
          const _Float16* pa2l = pa1h + 24576;
          const _Float16* pbh = feHI + (nt * 16 + l15) * sA + lk;
          const _Float16* pbl = feLO + (nt * 16 + l15) * sA + lk;
          for (int kt = 0; kt < ktt; kt++) {
            h8 A1h = *(const h8*)(pa1h + kt * 512);
            h8 A1l = *(const h8*)(pa1l + kt * 512);
            h8 A2h = *(const h8*)(pa2h + kt * 512);
            h8 A2l = *(const h8*)(pa2l + kt * 512);
            h8 Bh = *(const h8*)(pbh + kt * 32);
            h8 Bl = *(const h8*)(pbl + kt * 32);
            MFMA(d1r, A1h, Bh);
            MFMA(d2r, A1l, Bh); MFMA(d2r, A1h, Bl);
            MFMA(d1i, A2h, Bh);
            MFMA(d2i, A2l, Bh); MFMA(d2i, A2h, Bl);
          }
          int j = nt * 16 + l15;
          bool jv = j < cp1;
          for (int q = 0; q < 4; q++) {
            int row = (lane >> 4) * 4 + q;
            float re = jv ? (d1r[q] + d2r[q] * LSC) : 0.f;
            float im = jv ? (d1i[q] + d2i[q] * LSC) : 0.f;
            int base = row * sT + 2 * j;
            _Float16 rh = (_Float16)re, ih = (_Float16)im;
            ttHI[base] = rh; ttHI[base + 1] = ih;
            ttLO[base] = (_Float16)((re - (float)rh) * 2048.f);
            ttLO[base + 1] = (_Float16)((im - (float)ih) * 2048.f);
          }
        }
        __syncthreads();
        // ---- syn: Img[row][v] = sum_k2 alpha*Re(TT*w), then gelu
        for (int nt = wid; nt < (NSY >> 4); nt += NTT_ / 64) {
          f4 d1 = {0.f, 0.f, 0.f, 0.f}, d2 = d1;
          const _Float16* pah = ttHI + l15 * sT + lk;
          const _Float16* pal = ttLO + l15 * sT + lk;
          const _Float16* pbh = Wsy + (nt * kts) * 512 + lane * 8;
          const _Float16* pbl = pbh + 16384;
          for (int kt = 0; kt < kts; kt++) {
            h8 Ah = *(const h8*)(pah + kt * 32);
            h8 Al = *(const h8*)(pal + kt * 32);
            h8 Bh = *(const h8*)(pbh + kt * 512);
            h8 Bl = *(const h8*)(pbl + kt * 512);
            MFMA(d1, Ah, Bh);
            MFMA(d2, Al, Bh); MFMA(d2, Ah, Bl);
          }
          int v = nt * 16 + l15;
          bool vv = v < 2 * c;
          for (int q = 0; q < 4; q++) {
            int row = (lane >> 4) * 4 + q;
            float val = vv ? gelu_exact(d1[q] + d2[q] * LSC) : 0.f;
            _Float16 vh = (_Float16)val;
            sbHI[row * sA + v] = vh;
            sbLO[row * sA + v] = (_Float16)((val - (float)vh) * 2048.f);
          }
        }
        __syncthreads();
        // ---- ana: TB[row][k2] = sum_v SBa[row][v] * e^{-2pi i k2 v / r}
        for (int nt = wid; nt < (NAN_ >> 4); nt += NTT_ / 64) {
          f4 d1 = {0.f, 0.f, 0.f, 0.f}, d2 = d1;
          const _Float16* pah = sbHI + l15 * sA + lk;
          const _Float16* pal = sbLO + l15 * sA + lk;
          const _Float16* pbh = Wan + (nt * ktt) * 512 + lane * 8;
          const _Float16* pbl = pbh + 8192;
          for (int kt = 0; kt < ktt; kt++) {
            h8 Ah = *(const h8*)(pah + kt * 32);
            h8 Al = *(const h8*)(pal + kt * 32);
            h8 Bh = *(const h8*)(pbh + kt * 512);
            h8 Bl = *(const h8*)(pbl + kt * 512);
            MFMA(d1, Ah, Bh);
            MFMA(d2, Al, Bh); MFMA(d2, Ah, Bl);
          }
          int n = nt * 16 + l15;
          if (n < 2 * c2) {
            int k2 = n >> 1, pim = n & 1;
            for (int q = 0; q < 4; q++) {
              int row = (lane >> 4) * 4 + q;
              tbp[2 * (row * c2 + k2) + pim] = d1[q] + d2[q] * LSC;
            }
          }
        }
        __syncthreads();
        // ---- gacc (VALU): Gd[f][k2] += sum_i TB[i][k2] e^{-2pi i f u / r},
        //      u = u0 + 2i, u0 = 32p + par
        int ns = min(16, c - 16 * p);
        int u0 = 32 * p + par;
        for (int idx = tid; idx < m * c2; idx += NTT_) {
          int j = idx / c2, k2 = idx - j * c2;
          int f = (j < rp2) ? j : (r - rn2 + (j - rp2));
          float gr = 0.f, gi = 0.f;
          if (!first) { float2 gv = Gd[idx]; gr = gv.x; gi = gv.y; }
          int t = (int)(((long)f * u0) % r);
          int st = 2 * f; if (st >= r) st -= r;
          for (int i = 0; i < ns; i++) {
            float2 e = TB[i * c2 + k2];
            float co = tw[2 * t], si = tw[2 * t + 1];
            gr += e.x * co + e.y * si;
            gi += e.y * co - e.x * si;
            t += st; if (t >= r) t -= r;
          }
          Gd[idx] = make_float2(gr, gi);
        }
        first = false;
        __syncthreads();
      }
    }
  } else {
    // ---- r == 128: identity stage A (VALU, as before)
    float* SBa = big;
    auto do_analysis = [&](int ns) {
      for (int idx = tid; idx < ns * c2; idx += NTT_) {
        int k2 = idx % c2, i = idx / c2;
        const float* gp = SBa + i * r;
        float sk2 = (k2 & 1) ? -1.f : 1.f;
        float cb = tw[2 * k2], sbr = tw[2 * k2 + 1];
        int t2 = (2 * k2) % r;
        float cs = tw[2 * t2], ss = tw[2 * t2 + 1];
        float ca = 1.f, sa = 0.f;
        float ar = 0.f, ai = 0.f;
        int v = 0;
        for (; v + 1 < c; v += 2) {
          float f1 = fmaf(sk2, gp[v + c], gp[v]);
          ar += f1 * ca; ai -= f1 * sa;
          float f2 = fmaf(sk2, gp[v + 1 + c], gp[v + 1]);
          ar += f2 * cb; ai -= f2 * sbr;
          ROT(ca, sa, cs, ss); ROT(cb, sbr, cs, ss);
        }
        if (v < c) {
          float f1 = fmaf(sk2, gp[v + c], gp[v]);
          ar += f1 * ca; ai -= f1 * sa;
        }
        TB[idx] = make_float2(ar, ai);
      }
    };
    auto do_gaccum = [&](int ns, int ubase, bool fir) {
      for (int idx = tid; idx < m * c2; idx += NTT_) {
        int j = idx / c2, k2 = idx - j * c2;
        int f = (j < rp2) ? j : (r - rn2 + (j - rp2));
        float gr = 0.f, gi = 0.f;
        if (!fir) { float2 gv = Gd[idx]; gr = gv.x; gi = gv.y; }
        int t = (f * ubase) % r;
        for (int i = 0; i < ns; i++) {
          float2 e = TB[i * c2 + k2];
          float co = tw[2 * t], si = tw[2 * t + 1];
          gr += e.x * co + e.y * si;
          gi += e.y * co - e.x * si;
          t += f; if (t >= r) t -= r;
        }
        Gd[idx] = make_float2(gr, gi);
      }
    };
    const float* xc = x + (size_t)ch * 128 * 128;
    for (int ub = 0; ub < r; ub += NU) {
      for (int idx = tid; idx < NU * r; idx += NTT_) {
        int v = idx & 127, i = idx >> 7;
        SBa[i * r + v] = gelu_exact(xc[(ub + i) * 128 + v]);
      }
      __syncthreads();
      do_analysis(NU);
      __syncthreads();
      do_gaccum(NU, ub, ub == 0);
      __syncthreads();
    }
  }

  {
    float invr2 = 1.0f / ((float)r * (float)r);
    for (int idx = tid; idx < m * c2; idx += NTT_) { Gd[idx].x *= invr2; Gd[idx].y *= invr2; }
  }
  __syncthreads();

  // ---- C: streamed smoothing synthesis + 2x2 maxpool into P ----
  float* P = big;
  float* SBc = big + c * c;
  for (int ub = 0; ub < r; ub += NU) {
    int ns = min(NU, r - ub);
    for (int idx = tid; idx < ns * c2; idx += NTT_) {
      int k2 = idx % c2, i = idx / c2;
      int u = ub + i;
      float trr = 0.f, tii = 0.f;
      int t = 0;
      for (int j = 0; j < rp2; j++) {
        float2 e = Gd[j * c2 + k2];
        float co = tw[2 * t], si = tw[2 * t + 1];
        trr += e.x * co - e.y * si; tii += e.x * si + e.y * co;
        t += u; if (t >= r) t -= r;
      }
      t = (int)(((long)(r - rn2) * u) % r);
      for (int j = rp2; j < m; j++) {
        float2 e = Gd[j * c2 + k2];
        float co = tw[2 * t], si = tw[2 * t + 1];
        trr += e.x * co - e.y * si; tii += e.x * si + e.y * co;
        t += u; if (t >= r) t -= r;
      }
      TB[idx] = make_float2(trr, tii);
    }
    __syncthreads();
    for (int idx = tid; idx < ns * c; idx += NTT_) {
      int v = idx % c, i = idx / c;
      const float2* T2 = TB + i * c2;
      float base = T2[0].x;
      float cv = tw[2 * v], sv = tw[2 * v + 1];
      int t2 = (2 * v) % r;
      float cs = tw[2 * t2], ss = tw[2 * t2 + 1];
      float ca = cv, sa = sv, cb = cs, sbr = ss;
      float ea = 0.f, eb = 0.f;
      int k2 = 1;
      for (; k2 + 1 < c2; k2 += 2) {
        float2 e = T2[k2];
        float term = e.x * ca - e.y * sa;
        ea += term; eb -= term;
        e = T2[k2 + 1];
        float term2 = e.x * cb - e.y * sbr;
        ea += term2; eb += term2;
        ROT(ca, sa, cs, ss); ROT(cb, sbr, cs, ss);
      }
      if (k2 < c2) {
        float2 e = T2[k2];
        float term = e.x * ca - e.y * sa;
        ea += term; eb -= term;
      }
      SBc[i * r + v]     = base + 2.f * ea;
      SBc[i * r + v + c] = base + 2.f * eb;
    }
    __syncthreads();
    for (int idx = tid; idx < (ns >> 1) * c; idx += NTT_) {
      int jj = idx % c, i2 = idx / c;
      const float* s0p = SBc + (2 * i2) * r;
      const float* s1p = SBc + (2 * i2 + 1) * r;
      float pv = fmaxf(fmaxf(s0p[2 * jj], s0p[2 * jj + 1]), fmaxf(s1p[2 * jj], s1p[2 * jj + 1]));
      P[(ub / 2 + i2) * c + jj] = pv;
    }
    __syncthreads();
  }

  // ---- E: ring DFT of pooled image (P1 overlays Gd, which is now dead) ----
  float2* P1 = (float2*)gdp;
  int hp1 = h + 1;
  for (int idx = tid; idx < c * hp1; idx += NTT_) {
    int k2 = idx % hp1, i = idx / hp1;
    const float* prow = P + i * c;
    int dt = (2 * k2) % r;
    float cb = tw[2 * dt], sbr = tw[2 * dt + 1];
    int dt2 = (2 * dt) % r;
    float cs = tw[2 * dt2], ss = tw[2 * dt2 + 1];
    float ca = 1.f, sa = 0.f;
    float ar = 0.f, ai = 0.f;
    int jj = 0;
    for (; jj + 1 < c; jj += 2) {
      float p0 = prow[jj], q0 = prow[jj + 1];
      ar += p0 * ca; ai -= p0 * sa;
      ar += q0 * cb; ai -= q0 * sbr;
      ROT(ca, sa, cs, ss); ROT(cb, sbr, cs, ss);
    }
    if (jj < c) { float p0 = prow[jj]; ar += p0 * ca; ai -= p0 * sa; }
    P1[idx] = make_float2(ar, ai);
  }
  __syncthreads();
  float invcc = 1.0f / ((float)c * (float)c);
  float2* ringp = g_ring + ((size_t)ch * 57 + (size_t)((r - 16) >> 1)) * 132;
  auto ring_out = [&](int k1, int k2, int slot) {
    int dt = (2 * k1) % r;
    float cb = tw[2 * dt], sbr = tw[2 * dt + 1];
    int dt2 = (2 * dt) % r;
    float cs = tw[2 * dt2], ss = tw[2 * dt2 + 1];
    float ca = 1.f, sa = 0.f;
    float ar = 0.f, ai = 0.f;
    int i = 0;
    for (; i + 1 < c; i += 2) {
      float2 e = P1[i * hp1 + k2];
      ar += e.x * ca + e.y * sa; ai += e.y * ca - e.x * sa;
      float2 e2 = P1[(i + 1) * hp1 + k2];
      ar += e2.x * cb + e2.y * sbr; ai += e2.y * cb - e2.x * sbr;
      ROT(ca, sa, cs, ss); ROT(cb, sbr, cs, ss);
    }
    if (i < c) {
      float2 e = P1[i * hp1 + k2];
      ar += e.x * ca + e.y * sa; ai += e.y * ca - e.x * sa;
    }
    ringp[slot] = make_float2(ar * invcc, ai * invcc);
  };
  if (r == 16) {
    for (int idx = tid; idx < 40; idx += NTT_) ring_out(idx / 5, idx % 5, idx);
  } else {
    int nA = hp1, total = 2 * nA + c;
    for (int idx = tid; idx < total; idx += NTT_) {
      int k1, k2;
      if (idx < nA) { k1 = h; k2 = idx; }
      else if (idx < 2 * nA) { k1 = c - h; k2 = idx - nA; }
      else { k1 = idx - 2 * nA; k2 = h; }
      ring_out(k1, k2, idx);
    }
  }
}

// ---------------------------------------------------------------------------
// Final assembly: out = Hermitian-extension projection of x_out (no FFTs).
// ---------------------------------------------------------------------------
__device__ __forceinline__ float2 loadA(int ch, int k1, int k2) {
  int o = g_owner[k1 * 33 + k2];
  if (o < 0) return make_float2(0.f, 0.f);
  return g_ring[((size_t)ch * 57 + (o >> 8)) * 132 + (o & 255)];
}

__global__ __launch_bounds__(NT) void assemble_kernel(float* __restrict__ out) {
  size_t gid = (size_t)blockIdx.x * NT + threadIdx.x;
  if (gid >= (size_t)NCH * 4096) return;
  int ch = (int)(gid >> 12);
  int rem = (int)(gid & 4095);
  int k1 = rem >> 6, k2f = rem & 63;
  float2 v;
  if (k2f <= 32) {
    float2 a = loadA(ch, k1, k2f);
    if (k2f == 0 || k2f == 32) {
      float2 b = loadA(ch, (64 - k1) & 63, k2f);
      v = make_float2(0.5f * (a.x + b.x), 0.5f * (a.y - b.y));
    } else v = a;
  } else {
    float2 a = loadA(ch, (64 - k1) & 63, 64 - k2f);
    v = make_float2(a.x, -a.y);
  }
  out[2 * gid] = v.x;
  out[2 * gid + 1] = v.y;
}

// ---------------------------------------------------------------------------
static int lds_floats(int r) {
  int c = r >> 1, cp1 = c + 1, c2 = (c >> 1) + 1, m = c;
  int base = 2 * r + 2 * m * c2 + 2 * 16 * c2 + 4;
  int cph = c * c + 8 * r;
  int big;
  if (r == 128) {
    int sba = 8 * r;
    big = cph > sba ? cph : sba;
  } else {
    int KTT = 32 * ((2 * c + 31) >> 5);
    int NTP = 16 * ((cp1 + 15) >> 4);
    int KSY = 2 * NTP;
    // fp16 hi+lo pairs expressed in float units
    int apha = NTP * (KTT + 8) + 16 * (KSY + 8) + 16 * (KTT + 8);
    big = apha > cph ? apha : cph;
  }
  return base + big;
}

extern "C" void kernel_launch(void* const* d_in, const int* in_sizes, int n_in,
                              void* d_out, int out_size, void* d_ws, size_t ws_size,
                              hipStream_t stream) {
  (void)in_sizes; (void)n_in; (void)d_ws; (void)ws_size; (void)out_size;
  const float* x = (const float*)d_in[0];
  float* out = (float*)d_out;

  hipFuncSetAttribute(reinterpret_cast<const void*>(pipe_kernel<NT>),
                      hipFuncAttributeMaxDynamicSharedMemorySize, 160 * 1024);

  hipLaunchKernelGGL(owner_kernel, dim3(9), dim3(NT), 0, stream);
  hipLaunchKernelGGL(wprep_kernel, dim3(56), dim3(256), 0, stream);
  hipLaunchKernelGGL(r1_kernel, dim3(NCH * 8), dim3(NT), 0, stream, x);
  hipLaunchKernelGGL(r2_kernel, dim3(NCH * 9), dim3(NT), 0, stream);

  hipLaunchKernelGGL(pipe_kernel<NT>, dim3(15 * NCH), dim3(NT),
                     (size_t)lds_floats(126) * 4, stream, x, 126); // 98..126 (74KB -> 2 blk/CU)
  hipLaunchKernelGGL(pipe_kernel<NT>, dim3(1 * NCH), dim3(NT),
                     (size_t)lds_floats(128) * 4, stream, x, 128); // 128 (identity stage A)
  hipLaunchKernelGGL(pipe_kernel<NT>, dim3(16 * NCH), dim3(NT),
                     (size_t)lds_floats(96) * 4, stream, x, 96);   // 66..96
  hipLaunchKernelGGL(pipe_kernel<NT>, dim3(16 * NCH), dim3(NT),
                     (size_t)lds_floats(64) * 4, stream, x, 64);   // 34..64
  hipLaunchKernelGGL(pipe_kernel<NT>, dim3(9 * NCH), dim3(NT),
                     (size_t)lds_floats(32) * 4, stream, x, 32);   // 16..32

  hipLaunchKernelGGL(assemble_kernel, dim3((NCH * 4096) / NT), dim3(NT), 0, stream, out);
}

// Round 2
// 14086.195 us; speedup vs baseline: 1.8781x; 1.7750x over previous
//
#include <hip/hip_runtime.h>
#include <math.h>

#define NCH 2048
#define NT 256

typedef _Float16 h8 __attribute__((ext_vector_type(8)));
typedef float f4 __attribute__((ext_vector_type(4)));

#define MFMA(d, a, b) d = __builtin_amdgcn_mfma_f32_16x16x32_f16(a, b, d, 0, 0, 0)

// Static device scratch (avoids any assumption about ws_size).
__device__ float2 g_X[(size_t)NCH * 128 * 65];     // 136 MB
__device__ float2 g_Y[(size_t)NCH * 128 * 65];     // 136 MB
__device__ float2 g_ring[(size_t)NCH * 57 * 132];  // 123 MB
__device__ int    g_owner[64 * 33];
// Stage-A twiddle fragments, fp16 hi/lo (lo pre-scaled x2048).
// Per-res slot = 114688 fp16: [Wtt 8x8192][Wsyn 2x16384][Wana 2x8192]
__device__ _Float16 g_W[(size_t)56 * 114688];      // 12.8 MB
// C/E-phase tables per res (57 slots incl r=128), fp16 offsets:
//   0: WDhi[16384] 16384: WDlo | 32768: Wc2hi[12288] 45056: Wc2lo
//   57344: WEhi[5120] 62464: WElo  (total 67584)
__device__ _Float16 g_W2[(size_t)57 * 67584];      // 7.7 MB
// Per-block TB fragment scratch: [ntB][ktt2][hi 512 | lo 512] fp16
__device__ _Float16 g_TBF[(size_t)32768 * 20480];  // 1.34 GB

__device__ __forceinline__ float gelu_exact(float v) {
  return 0.5f * v * (1.0f + erff(v * 0.70710678118654752440f));
}

// incremental complex rotation: (co,si) *= (cs,ss)
#define ROT(co, si, cs, ss) { float _n = co * cs - si * ss; si = si * cs + co * ss; co = _n; }

// ---------------------------------------------------------------------------
// R1: row-wise DFT along v: Y[ch,u,k2] = sum_v x[ch,u,v] e^{-2pi i k2 v/128}
// ---------------------------------------------------------------------------
__global__ __launch_bounds__(NT) void r1_kernel(const float* __restrict__ x) {
  __shared__ float xb[16 * 128];
  __shared__ float tw[256];
  int ch = blockIdx.x >> 3, grp = blockIdx.x & 7;
  int tid = threadIdx.x;
  for (int t = tid; t < 128; t += NT) {
    float s, co; sincosf(6.283185307179586f * (float)t / 128.0f, &s, &co);
    tw[2 * t] = co; tw[2 * t + 1] = s;
  }
  const float* xp = x + ((size_t)ch * 128 + grp * 16) * 128;
  for (int i = tid; i < 16 * 128; i += NT) xb[i] = xp[i];
  __syncthreads();
  for (int idx = tid; idx < 16 * 65; idx += NT) {
    int u = idx / 65, k2 = idx - 65 * u;
    const float* row = xb + u * 128;
    float cb = tw[2 * k2], sbr = tw[2 * k2 + 1];
    int t2 = (2 * k2) & 127;
    float cs = tw[2 * t2], ss = tw[2 * t2 + 1];
    float ca = 1.f, sa = 0.f;
    float ar = 0.f, ai = 0.f;
    for (int v = 0; v < 128; v += 2) {
      float x0 = row[v], x1 = row[v + 1];
      ar += x0 * ca; ai -= x0 * sa;
      ar += x1 * cb; ai -= x1 * sbr;
      ROT(ca, sa, cs, ss); ROT(cb, sbr, cs, ss);
    }
    g_Y[((size_t)ch * 128 + grp * 16 + u) * 65 + k2] = make_float2(ar, ai);
  }
}

// ---------------------------------------------------------------------------
// R2: col-wise DFT along u + 1/16384 norm. Pairs k1 and k1+64 via (-1)^u.
// ---------------------------------------------------------------------------
__global__ __launch_bounds__(NT) void r2_kernel() {
  __shared__ float2 yb[128 * 8];
  __shared__ float tw[256];
  int ch = blockIdx.x / 9, cg = blockIdx.x - 9 * ch;
  int c0 = cg * 8, nc = min(8, 65 - c0);
  int tid = threadIdx.x;
  for (int t = tid; t < 128; t += NT) {
    float s, co; sincosf(6.283185307179586f * (float)t / 128.0f, &s, &co);
    tw[2 * t] = co; tw[2 * t + 1] = s;
  }
  for (int i = tid; i < 128 * nc; i += NT) {
    int u = i / nc, j = i - nc * u;
    yb[u * 8 + j] = g_Y[((size_t)ch * 128 + u) * 65 + c0 + j];
  }
  __syncthreads();
  const float inv = 1.0f / 16384.0f;
  for (int idx = tid; idx < 64 * nc; idx += NT) {
    int k1 = idx & 63, j = idx >> 6;
    float cb = tw[2 * k1], sbr = tw[2 * k1 + 1];
    int t2 = (2 * k1) & 127;
    float cs = tw[2 * t2], ss = tw[2 * t2 + 1];
    float ca = 1.f, sa = 0.f;
    float ar = 0.f, ai = 0.f, br = 0.f, bi = 0.f;
    for (int u = 0; u < 128; u += 2) {
      float2 e = yb[u * 8 + j];
      float pr = e.x * ca + e.y * sa, pi2 = e.y * ca - e.x * sa;
      ar += pr; ai += pi2; br += pr; bi += pi2;
      e = yb[(u + 1) * 8 + j];
      float pr2 = e.x * cb + e.y * sbr, pi3 = e.y * cb - e.x * sbr;
      ar += pr2; ai += pi3; br -= pr2; bi -= pi3;
      ROT(ca, sa, cs, ss); ROT(cb, sbr, cs, ss);
    }
    g_X[((size_t)ch * 128 + k1) * 65 + c0 + j]      = make_float2(ar * inv, ai * inv);
    g_X[((size_t)ch * 128 + k1 + 64) * 65 + c0 + j] = make_float2(br * inv, bi * inv);
  }
}

// ---------------------------------------------------------------------------
// Owner map (reference's sequential overwrite order).
// ---------------------------------------------------------------------------
__device__ __forceinline__ int owner_slot(int rr, int k2, int ri) {
  if (ri == 0) {
    if (k2 <= 4) {
      if (rr <= 3) return rr * 5 + k2;
      if (rr >= 60) return (rr - 56) * 5 + k2;
    }
    return -1;
  }
  int res = 16 + 2 * ri, c = res / 2, h = c / 2;
  if (c & 1) {
    if (rr == h && k2 <= h) return k2;
    if (rr == 64 - h && k2 <= h) return (h + 1) + k2;
    if (k2 == h) {
      if (rr <= h) return 2 * (h + 1) + rr;
      if (rr >= 64 - h) return 2 * (h + 1) + (rr - 64 + c);
    }
  } else {
    if (rr == 64 - h && k2 <= h) return (h + 1) + k2;
    if (k2 == h) {
      if (rr >= 64 - h) return 2 * (h + 1) + (rr - 64 + c);
      if (rr < h) return 2 * (h + 1) + rr;
    }
  }
  return -1;
}

__global__ __launch_bounds__(NT) void owner_kernel() {
  int cell = blockIdx.x * NT + threadIdx.x;
  if (cell >= 64 * 33) return;
  int rr = cell / 33, k2 = cell - 33 * (cell / 33);
  int result = -1;
  for (int ri = 56; ri >= 0 && result < 0; ri--) {
    int slot = owner_slot(rr, k2, ri);
    if (slot >= 0) result = ri * 256 + slot;
  }
  g_owner[cell] = result;
}

// ---------------------------------------------------------------------------
// Twiddle-fragment precompute, r = 16..128 step 2 (ri = (r-16)/2).
// Fragment packing (16x32 tile = 512 fp16): value(row/col = l&15,
// k = (l>>4)*8 + e).  hi/lo split: lo = (v - (f32)(f16)v) * 2048.
// ---------------------------------------------------------------------------
__global__ __launch_bounds__(256) void wprep_kernel() {
  int r = 16 + 2 * blockIdx.x;
  int c = r >> 1, cp1 = c + 1, c2 = (c >> 1) + 1;
  const float TP = 6.283185307179586f;
  const float PIF_ = 3.14159265358979f;
  float invr = 1.0f / (float)r;

  if (r <= 126) {
    int KTT = 32 * ((2 * c + 31) >> 5);
    int NTP = 16 * ((cp1 + 15) >> 4);
    int KSY = 2 * NTP;
    int NSY = KTT;
    int NAN_ = 16 * ((2 * c2 + 15) >> 4);
    int MT = (c + 15) >> 4;
    int ktt = KTT >> 5, kts = KSY >> 5;
    _Float16* W = g_W + (size_t)blockIdx.x * 114688;

    // ---- Wtt: s = par*4 + v*2 + h.  A1=(cos,-sin) -> re, A2=(sin,cos) -> im
    int tot = 8 * MT * ktt * 64;
    for (int fi = threadIdx.x; fi < tot; fi += 256) {
      int l = fi & 63, rest = fi >> 6;
      int kt = rest % ktt; rest /= ktt;
      int mt = rest % MT;  rest /= MT;
      int s = rest;
      int hh = s & 1, vv = (s >> 1) & 1, par = s >> 2;
      int i = mt * 16 + (l & 15);
      int u = 2 * i + par;
      int kb = kt * 32 + (l >> 4) * 8;
      h8 o;
      for (int e = 0; e < 8; e++) {
        int k = kb + e, kk = k >> 1, im = k & 1;
        float val = 0.f;
        if (i < c && kk < c) {
          int tm = (u * kk) % r;
          float sn, cs; sincosf(TP * (float)tm * invr, &sn, &cs);
          val = (vv == 0) ? (im ? -sn : cs) : (im ? cs : sn);
        }
        if (hh) { float hi = (float)(_Float16)val; val = (val - hi) * 2048.f; }
        o[e] = (_Float16)val;
      }
      *(h8*)(W + s * 8192 + (mt * ktt + kt) * 512 + l * 8) = o;
    }
    // ---- Wsyn (B-type): k-interleave (2k2)=alpha*cos, (2k2+1)=-alpha*sin
    int nts = NSY >> 4;
    tot = 2 * nts * kts * 64;
    for (int fi = threadIdx.x; fi < tot; fi += 256) {
      int l = fi & 63, rest = fi >> 6;
      int kt = rest % kts; rest /= kts;
      int nt = rest % nts; rest /= nts;
      int hh = rest;
      int v = nt * 16 + (l & 15);
      int kb = kt * 32 + (l >> 4) * 8;
      h8 o;
      for (int e = 0; e < 8; e++) {
        int k = kb + e, k2 = k >> 1, im = k & 1;
        float val = 0.f;
        if (k2 <= c) {
          int tm = (v * k2) % r;
          if (im) {
            if (k2 != 0 && k2 != c) val = -2.f * sinf(TP * (float)tm * invr);
          } else {
            float a = (k2 == 0 || k2 == c) ? 1.f : 2.f;
            val = a * cosf(TP * (float)tm * invr);
          }
        }
        if (hh) { float hi = (float)(_Float16)val; val = (val - hi) * 2048.f; }
        o[e] = (_Float16)val;
      }
      *(h8*)(W + 65536 + hh * 16384 + (nt * kts + kt) * 512 + l * 8) = o;
    }
    // ---- Wana (B-type): col n: even->cos(2pi k2 v/r), odd->-sin; k dim = v
    int nta = NAN_ >> 4;
    tot = 2 * nta * ktt * 64;
    for (int fi = threadIdx.x; fi < tot; fi += 256) {
      int l = fi & 63, rest = fi >> 6;
      int kt = rest % ktt; rest /= ktt;
      int nt = rest % nta; rest /= nta;
      int hh = rest;
      int n = nt * 16 + (l & 15);
      int k2 = n >> 1, im = n & 1;
      int kb = kt * 32 + (l >> 4) * 8;
      h8 o;
      for (int e = 0; e < 8; e++) {
        int v = kb + e;
        float val = 0.f;
        if (n < 2 * c2 && v < r) {
          int tm = (k2 * v) % r;
          val = im ? -sinf(TP * (float)tm * invr) : cosf(TP * (float)tm * invr);
        }
        if (hh) { float hi = (float)(_Float16)val; val = (val - hi) * 2048.f; }
        o[e] = (_Float16)val;
      }
      *(h8*)(W + 98304 + hh * 8192 + (nt * ktt + kt) * 512 + l * 8) = o;
    }
  }

  // ---- new C/E-phase tables in g_W2 ----
  _Float16* W2 = g_W2 + (size_t)blockIdx.x * 67584;
  int mtD = (r + 15) >> 4, ktD = (r + 31) >> 5;
  {
    // WD (A-type): Dirichlet K(u'-u) * 64/r^2.  K(0)=c, else sin(pi c d/r)/sin(pi d/r)
    float sK = 64.0f / ((float)r * (float)r);
    int tot = 2 * mtD * ktD * 64;
    for (int fi = threadIdx.x; fi < tot; fi += 256) {
      int l = fi & 63, rest = fi >> 6;
      int kt = rest % ktD; rest /= ktD;
      int mt = rest % mtD; rest /= mtD;
      int hh = rest;
      int up = mt * 16 + (l & 15);
      int kb = kt * 32 + (l >> 4) * 8;
      h8 o;
      for (int e = 0; e < 8; e++) {
        int u = kb + e;
        float val = 0.f;
        if (up < r && u < r) {
          int d = up - u;
          if (d == 0) val = (float)c * sK;
          else {
            int nm = (c * d) % (2 * r);
            val = sinf(PIF_ * (float)nm * invr) / sinf(PIF_ * (float)d * invr) * sK;
          }
        }
        if (hh) { float hi = (float)(_Float16)val; val = (val - hi) * 2048.f; }
        o[e] = (_Float16)val;
      }
      *(h8*)(W2 + hh * 16384 + (mt * ktD + kt) * 512 + l * 8) = o;
    }
  }
  {
    // Wc2 (B-type): col v, k=2k2+im: [2k2]=alpha*cos(2pi v k2/r), [2k2+1]=-alpha*sin
    int ntC = mtD, kC = (2 * c2 + 31) >> 5;
    int tot = 2 * ntC * kC * 64;
    for (int fi = threadIdx.x; fi < tot; fi += 256) {
      int l = fi & 63, rest = fi >> 6;
      int kt = rest % kC; rest /= kC;
      int nt = rest % ntC; rest /= ntC;
      int hh = rest;
      int v = nt * 16 + (l & 15);
      int kb = kt * 32 + (l >> 4) * 8;
      h8 o;
      for (int e = 0; e < 8; e++) {
        int k = kb + e, k2 = k >> 1, im = k & 1;
        float val = 0.f;
        if (v < r && k2 < c2) {
          float al = (k2 == 0) ? 1.f : 2.f;
          int tm = (v * k2) % r;
          val = im ? -al * sinf(TP * (float)tm * invr) : al * cosf(TP * (float)tm * invr);
        }
        if (hh) { float hi = (float)(_Float16)val; val = (val - hi) * 2048.f; }
        o[e] = (_Float16)val;
      }
      *(h8*)(W2 + 32768 + hh * 12288 + (nt * kC + kt) * 512 + l * 8) = o;
    }
  }
  {
    // WE (B-type): col n=2k2+im, k=v: cos(2pi k2 v/c) / -sin
    int hq = c >> 1;
    int ntE = (2 * (hq + 1) + 15) >> 4, kE = (c + 31) >> 5;
    float invc = 1.0f / (float)c;
    int tot = 2 * ntE * kE * 64;
    for (int fi = threadIdx.x; fi < tot; fi += 256) {
      int l = fi & 63, rest = fi >> 6;
      int kt = rest % kE; rest /= kE;
      int nt = rest % ntE; rest /= ntE;
      int hh = rest;
      int n = nt * 16 + (l & 15);
      int k2 = n >> 1, im = n & 1;
      int kb = kt * 32 + (l >> 4) * 8;
      h8 o;
      for (int e = 0; e < 8; e++) {
        int v = kb + e;
        float val = 0.f;
        if (n < 2 * (hq + 1) && v < c) {
          int tm = (k2 * v) % c;
          val = im ? -sinf(TP * (float)tm * invc) : cosf(TP * (float)tm * invc);
        }
        if (hh) { float hi = (float)(_Float16)val; val = (val - hi) * 2048.f; }
        o[e] = (_Float16)val;
      }
      *(h8*)(W2 + 57344 + hh * 5120 + (nt * kE + kt) * 512 + l * 8) = o;
    }
  }
}

// ---------------------------------------------------------------------------
// Per-(channel,res) pipeline.  Stage A: TTmm -> syn+gelu -> ana (MFMA), ana
// writes phase-rotated TB fragments to global TBF.  C-phase: Dirichlet-fused
// smoothing (one real MFMA matmul), row synthesis (MFMA), maxpool, pooled-DFT
// (MFMA), ring outputs (VALU, tiny).
// ---------------------------------------------------------------------------
template <int NTT_>
__global__ __launch_bounds__(NTT_) void pipe_kernel(const float* __restrict__ x, int res_hi) {
  const int NU = 8;
  int rorder = blockIdx.x / NCH;
  int ch = blockIdx.x - rorder * NCH;
  int r = res_hi - 2 * rorder;
  const int tid = threadIdx.x;
  const int lane = tid & 63;
  const int wid = tid >> 6;
  const int l15 = lane & 15;
  const int lk = (lane >> 4) << 3;
  int c = r >> 1, cp1 = c + 1, c2 = (c >> 1) + 1, h = c >> 1;
  bool is128 = (r == 128);
  int ri = (r - 16) >> 1;

  const int ktt2 = (r + 31) >> 5;       // TBF K-tiles (K = u over r)
  const int ntB  = (2 * c2 + 15) >> 4;  // TBF / ana n-tiles
  const int mtD  = (r + 15) >> 4;       // u'-tiles
  const int kC   = (2 * c2 + 31) >> 5;  // C2 K-tiles
  const int mtE  = (c + 15) >> 4;
  const int kE   = (c + 31) >> 5;
  const float srot = (c & 1) ? 0.f : 1.f;   // sigma = 0 (c odd) / -1 (c even)
  const float LSC = 4.8828125e-4f;          // 1/2048
  const float PIF_ = 3.14159265358979f;

  extern __shared__ float lds[];
  float* tw = lds;                          // 2r
  float* gdp = tw + 2 * r;                  // P1 overlay region (2*c*c2 floats)
  float* tbp = gdp + 2 * c * c2;            // TB f32 (128-path) 2*16*c2
  float2* TB = (float2*)tbp;
  float* big = (float*)(((size_t)(tbp + 2 * 16 * c2) + 15) & ~(size_t)15);

  _Float16* tbf = g_TBF + (size_t)blockIdx.x * 20480;
  {
    f4 z = {0.f, 0.f, 0.f, 0.f};
    int ntot = ntB * ktt2 * 128;
    for (int i = tid; i < ntot; i += NTT_) *(f4*)(tbf + i * 8) = z;
  }

  for (int t = tid; t < r; t += NTT_) {
    float s, co; sincosf(6.283185307179586f * (float)t / (float)r, &s, &co);
    tw[2 * t] = co; tw[2 * t + 1] = s;
  }
  __syncthreads();

  const float2* Xc = g_X + (size_t)ch * (128 * 65);

  if (!is128) {
    const int KTT = 32 * ((2 * c + 31) >> 5);
    const int NTP = 16 * ((cp1 + 15) >> 4);
    const int KSY = 2 * NTP;
    const int NSY = KTT;
    const int MT = (c + 15) >> 4;
    const int ktt = KTT >> 5, kts = KSY >> 5;
    const int sA = KTT + 8, sT = KSY + 8;
    const _Float16* Wslot = g_W + (size_t)ri * 114688;
    const _Float16* Wsy = Wslot + 65536;
    const _Float16* Wan = Wslot + 98304;
    _Float16* feHI = (_Float16*)big;
    _Float16* feLO = feHI + NTP * sA;
    _Float16* ttHI = feLO + NTP * sA;
    _Float16* ttLO = ttHI + 16 * sT;
    _Float16* sbHI = ttLO + 16 * sT;
    _Float16* sbLO = sbHI + 16 * sA;
    int halfK = KTT >> 1;

    for (int par = 0; par < 2; par++) {
      // ---- folded crop fe = pa +/- pb, transposed [j][2kk], hi/lo
      for (int idx = tid; idx < NTP * halfK; idx += NTT_) {
        int j = idx % NTP, kk = idx / NTP;
        float fx = 0.f, fy = 0.f;
        if (j < cp1 && kk < c) {
          float2 e1 = Xc[(size_t)kk * 65 + j];
          float2 e2 = Xc[(size_t)(128 - c + kk) * 65 + j];
          fx = par ? (e1.x - e2.x) : (e1.x + e2.x);
          fy = par ? (e1.y - e2.y) : (e1.y + e2.y);
        }
        int base = j * sA + 2 * kk;
        _Float16 xh = (_Float16)fx, yh = (_Float16)fy;
        feHI[base] = xh; feHI[base + 1] = yh;
        feLO[base] = (_Float16)((fx - (float)xh) * 2048.f);
        feLO[base + 1] = (_Float16)((fy - (float)yh) * 2048.f);
      }
      __syncthreads();

      for (int p = 0; p < MT; p++) {
        // ---- TTmm
        for (int nt = wid; nt < (NTP >> 4); nt += NTT_ / 64) {
          f4 d1r = {0.f, 0.f, 0.f, 0.f}, d2r = d1r, d1i = d1r, d2i = d1r;
          const _Float16* pa1h = Wslot + (par * 4 + 0) * 8192 + (p * ktt) * 512 + lane * 8;
          const _Float16* pa1l = pa1h + 8192;
          const _Float16* pa2h = pa1h + 16384;
          const _Float16* pa2l = pa1h + 24576;
          const _Float16* pbh = feHI + (nt * 16 + l15) * sA + lk;
          const _Float16* pbl = feLO + (nt * 16 + l15) * sA + lk;
          for (int kt = 0; kt < ktt; kt++) {
            h8 A1h = *(const h8*)(pa1h + kt * 512);
            h8 A1l = *(const h8*)(pa1l + kt * 512);
            h8 A2h = *(const h8*)(pa2h + kt * 512);
            h8 A2l = *(const h8*)(pa2l + kt * 512);
            h8 Bh = *(const h8*)(pbh + kt * 32);
            h8 Bl = *(const h8*)(pbl + kt * 32);
            MFMA(d1r, A1h, Bh);
            MFMA(d2r, A1l, Bh); MFMA(d2r, A1h, Bl);
            MFMA(d1i, A2h, Bh);
            MFMA(d2i, A2l, Bh); MFMA(d2i, A2h, Bl);
          }
          int j = nt * 16 + l15;
          bool jv = j < cp1;
          for (int q = 0; q < 4; q++) {
            int row = (lane >> 4) * 4 + q;
            float re = jv ? (d1r[q] + d2r[q] * LSC) : 0.f;
            float im = jv ? (d1i[q] + d2i[q] * LSC) : 0.f;
            int base = row * sT + 2 * j;
            _Float16 rh = (_Float16)re, ih = (_Float16)im;
            ttHI[base] = rh; ttHI[base + 1] = ih;
            ttLO[base] = (_Float16)((re - (float)rh) * 2048.f);
            ttLO[base + 1] = (_Float16)((im - (float)ih) * 2048.f);
          }
        }
        __syncthreads();
        // ---- syn + gelu
        for (int nt = wid; nt < (NSY >> 4); nt += NTT_ / 64) {
          f4 d1 = {0.f, 0.f, 0.f, 0.f}, d2 = d1;
          const _Float16* pah = ttHI + l15 * sT + lk;
          const _Float16* pal = ttLO + l15 * sT + lk;
          const _Float16* pbh = Wsy + (nt * kts) * 512 + lane * 8;
          const _Float16* pbl = pbh + 16384;
          for (int kt = 0; kt < kts; kt++) {
            h8 Ah = *(const h8*)(pah + kt * 32);
            h8 Al = *(const h8*)(pal + kt * 32);
            h8 Bh = *(const h8*)(pbh + kt * 512);
            h8 Bl = *(const h8*)(pbl + kt * 512);
            MFMA(d1, Ah, Bh);
            MFMA(d2, Al, Bh); MFMA(d2, Ah, Bl);
          }
          int v = nt * 16 + l15;
          bool vv = v < 2 * c;
          for (int q = 0; q < 4; q++) {
            int row = (lane >> 4) * 4 + q;
            float val = vv ? gelu_exact(d1[q] + d2[q] * LSC) : 0.f;
            _Float16 vh = (_Float16)val;
            sbHI[row * sA + v] = vh;
            sbLO[row * sA + v] = (_Float16)((val - (float)vh) * 2048.f);
          }
        }
        __syncthreads();
        // ---- ana -> TBF fragments (with sigma phase rotation)
        for (int nt = wid; nt < ntB; nt += NTT_ / 64) {
          f4 d1 = {0.f, 0.f, 0.f, 0.f}, d2 = d1;
          const _Float16* pah = sbHI + l15 * sA + lk;
          const _Float16* pal = sbLO + l15 * sA + lk;
          const _Float16* pbh = Wan + (nt * ktt) * 512 + lane * 8;
          const _Float16* pbl = pbh + 8192;
          for (int kt = 0; kt < ktt; kt++) {
            h8 Ah = *(const h8*)(pah + kt * 32);
            h8 Al = *(const h8*)(pal + kt * 32);
            h8 Bh = *(const h8*)(pbh + kt * 512);
            h8 Bl = *(const h8*)(pbl + kt * 512);
            MFMA(d1, Ah, Bh);
            MFMA(d2, Al, Bh); MFMA(d2, Ah, Bl);
          }
          int n = nt * 16 + l15;
          for (int q = 0; q < 4; q++) {
            float val = d1[q] + d2[q] * LSC;
            float pr = __shfl_xor(val, 1);
            int row = (lane >> 4) * 4 + q;
            int u = 32 * p + par + 2 * row;
            float sf_, cf_;
            sincosf(srot * PIF_ * (float)u / (float)r, &sf_, &cf_);
            float out = val * cf_ + ((n & 1) ? pr * sf_ : -pr * sf_);
            if (n < 2 * c2) {
              int kin = u & 31;
              int pos = ((n >> 4) * ktt2 + (u >> 5)) * 1024 + ((n & 15) + 16 * (kin >> 3)) * 8 + (kin & 7);
              _Float16 vh = (_Float16)out;
              tbf[pos] = vh;
              tbf[pos + 512] = (_Float16)((out - (float)vh) * 2048.f);
            }
          }
        }
        __syncthreads();
      }
    }
  } else {
    // ---- r == 128: identity stage A (VALU analysis) -> TBF
    const float* xc = x + (size_t)ch * 128 * 128;
    float* SBa = big;
    auto do_analysis = [&](int ns) {
      for (int idx = tid; idx < ns * c2; idx += NTT_) {
        int k2 = idx % c2, i = idx / c2;
        const float* gp = SBa + i * r;
        float sk2 = (k2 & 1) ? -1.f : 1.f;
        float cb = tw[2 * k2], sbr = tw[2 * k2 + 1];
        int t2 = (2 * k2) % r;
        float cs = tw[2 * t2], ss = tw[2 * t2 + 1];
        float ca = 1.f, sa = 0.f;
        float ar = 0.f, ai = 0.f;
        int v = 0;
        for (; v + 1 < c; v += 2) {
          float f1 = fmaf(sk2, gp[v + c], gp[v]);
          ar += f1 * ca; ai -= f1 * sa;
          float f2 = fmaf(sk2, gp[v + 1 + c], gp[v + 1]);
          ar += f2 * cb; ai -= f2 * sbr;
          ROT(ca, sa, cs, ss); ROT(cb, sbr, cs, ss);
        }
        if (v < c) {
          float f1 = fmaf(sk2, gp[v + c], gp[v]);
          ar += f1 * ca; ai -= f1 * sa;
        }
        TB[idx] = make_float2(ar, ai);
      }
    };
    for (int ub = 0; ub < r; ub += NU) {
      for (int idx = tid; idx < NU * r; idx += NTT_) {
        int v = idx & 127, i = idx >> 7;
        SBa[i * r + v] = gelu_exact(xc[(ub + i) * 128 + v]);
      }
      __syncthreads();
      do_analysis(NU);
      __syncthreads();
      for (int idx = tid; idx < NU * c2; idx += NTT_) {
        int k2 = idx % c2, i = idx / c2;
        float2 e = TB[i * c2 + k2];
        int u = ub + i;
        float sf_, cf_;
        sincosf(PIF_ * (float)u / (float)r, &sf_, &cf_);
        float re = e.x * cf_ - e.y * sf_;
        float im_ = e.x * sf_ + e.y * cf_;
        int kin = u & 31, kt = u >> 5;
        int n0 = 2 * k2;
        int pos0 = ((n0 >> 4) * ktt2 + kt) * 1024 + ((n0 & 15) + 16 * (kin >> 3)) * 8 + (kin & 7);
        _Float16 vh = (_Float16)re;
        tbf[pos0] = vh; tbf[pos0 + 512] = (_Float16)((re - (float)vh) * 2048.f);
        int n1 = n0 + 1;
        int pos1 = ((n1 >> 4) * ktt2 + kt) * 1024 + ((n1 & 15) + 16 * (kin >> 3)) * 8 + (kin & 7);
        vh = (_Float16)im_;
        tbf[pos1] = vh; tbf[pos1 + 512] = (_Float16)((im_ - (float)vh) * 2048.f);
      }
      __syncthreads();
    }
  }

  // ---- C-phase: per u'-tile: Dirichlet matmul -> T, synthesis -> S, maxpool
  _Float16* tAhi = (_Float16*)big;
  _Float16* tAlo = tAhi + kC * 512;
  float* Sf = big + kC * 512;
  float* paf = Sf + 16 * r;
  _Float16* pAhi = (_Float16*)paf;
  _Float16* pAlo = pAhi + mtE * kE * 512;
  for (int i = tid; i < kC * 512; i += NTT_) ((float*)tAhi)[i] = 0.f;
  for (int i = tid; i < mtE * kE * 512; i += NTT_) paf[i] = 0.f;
  __syncthreads();

  const _Float16* WDhi = g_W2 + (size_t)ri * 67584;
  const _Float16* WDlo = WDhi + 16384;
  const _Float16* Wc2hi = WDhi + 32768;
  const _Float16* Wc2lo = WDhi + 45056;
  const _Float16* WEhi = WDhi + 57344;
  const _Float16* WElo = WDhi + 62464;

  for (int mt = 0; mt < mtD; mt++) {
    // Dirichlet (real K) matmul: T[mt*16+ul][n], unscale 1/64, rotate, -> tA
    for (int nt = wid; nt < ntB; nt += NTT_ / 64) {
      f4 d1 = {0.f, 0.f, 0.f, 0.f}, d2 = d1;
      const _Float16* pah = WDhi + (mt * ktt2) * 512 + lane * 8;
      const _Float16* pal = WDlo + (mt * ktt2) * 512 + lane * 8;
      const _Float16* pbb = tbf + (nt * ktt2) * 1024 + lane * 8;
      for (int kt = 0; kt < ktt2; kt++) {
        h8 Ah = *(const h8*)(pah + kt * 512);
        h8 Al = *(const h8*)(pal + kt * 512);
        h8 Bh = *(const h8*)(pbb + kt * 1024);
        h8 Bl = *(const h8*)(pbb + kt * 1024 + 512);
        MFMA(d1, Ah, Bh); MFMA(d2, Al, Bh); MFMA(d2, Ah, Bl);
      }
      int n = nt * 16 + l15;
      for (int q = 0; q < 4; q++) {
        float val = (d1[q] + d2[q] * LSC) * 0.015625f;
        float pr = __shfl_xor(val, 1);
        int ul = (lane >> 4) * 4 + q;
        int up = mt * 16 + ul;
        float sf_, cf_;
        sincosf(-srot * PIF_ * (float)up / (float)r, &sf_, &cf_);
        float out = val * cf_ + ((n & 1) ? pr * sf_ : -pr * sf_);
        if (n < 2 * c2) {
          int pos = (n >> 5) * 512 + (ul + 16 * ((n & 31) >> 3)) * 8 + (n & 7);
          _Float16 vh = (_Float16)out;
          tAhi[pos] = vh;
          tAlo[pos] = (_Float16)((out - (float)vh) * 2048.f);
        }
      }
    }
    __syncthreads();
    // row synthesis: S[ul][v]
    for (int nt = wid; nt < mtD; nt += NTT_ / 64) {
      f4 d1 = {0.f, 0.f, 0.f, 0.f}, d2 = d1;
      for (int kt = 0; kt < kC; kt++) {
        h8 Ah = *(const h8*)(tAhi + kt * 512 + lane * 8);
        h8 Al = *(const h8*)(tAlo + kt * 512 + lane * 8);
        h8 Bh = *(const h8*)(Wc2hi + (nt * kC + kt) * 512 + lane * 8);
        h8 Bl = *(const h8*)(Wc2lo + (nt * kC + kt) * 512 + lane * 8);
        MFMA(d1, Ah, Bh); MFMA(d2, Al, Bh); MFMA(d2, Ah, Bl);
      }
      int v = nt * 16 + l15;
      if (v < r) {
        for (int q = 0; q < 4; q++) {
          int ul = (lane >> 4) * 4 + q;
          Sf[ul * r + v] = d1[q] + d2[q] * LSC;
        }
      }
    }
    __syncthreads();
    // 2x2 maxpool -> P A-fragments
    for (int idx = tid; idx < 8 * c; idx += NTT_) {
      int jj = idx % c, i2 = idx / c;
      const float* s0p = Sf + (2 * i2) * r;
      const float* s1p = Sf + (2 * i2 + 1) * r;
      float pv = fmaxf(fmaxf(s0p[2 * jj], s0p[2 * jj + 1]),
                       fmaxf(s1p[2 * jj], s1p[2 * jj + 1]));
      int i = mt * 8 + i2;
      int pos = ((i >> 4) * kE + (jj >> 5)) * 512 + ((i & 15) + 16 * ((jj & 31) >> 3)) * 8 + (jj & 7);
      _Float16 vh = (_Float16)pv;
      pAhi[pos] = vh;
      pAlo[pos] = (_Float16)((pv - (float)vh) * 2048.f);
    }
    __syncthreads();
  }

  // ---- E: pooled-image row DFT (MFMA) -> P1 (overlays gdp)
  int ntE = ntB;
  for (int t2 = wid; t2 < mtE * ntE; t2 += NTT_ / 64) {
    int mt = t2 / ntE, nt = t2 - mt * ntE;
    f4 d1 = {0.f, 0.f, 0.f, 0.f}, d2 = d1;
    for (int kt = 0; kt < kE; kt++) {
      h8 Ah = *(const h8*)(pAhi + (mt * kE + kt) * 512 + lane * 8);
      h8 Al = *(const h8*)(pAlo + (mt * kE + kt) * 512 + lane * 8);
      h8 Bh = *(const h8*)(WEhi + (nt * kE + kt) * 512 + lane * 8);
      h8 Bl = *(const h8*)(WElo + (nt * kE + kt) * 512 + lane * 8);
      MFMA(d1, Ah, Bh); MFMA(d2, Al, Bh); MFMA(d2, Ah, Bl);
    }
    int n = nt * 16 + l15;
    if (n < 2 * c2) {
      for (int q = 0; q < 4; q++) {
        int i = mt * 16 + (lane >> 4) * 4 + q;
        if (i < c) gdp[(i * c2 + (n >> 1)) * 2 + (n & 1)] = d1[q] + d2[q] * LSC;
      }
    }
  }
  __syncthreads();

  // ---- ring outputs (VALU, tiny)
  float2* P1 = (float2*)gdp;
  int hp1 = h + 1;
  float invcc = 1.0f / ((float)c * (float)c);
  float2* ringp = g_ring + ((size_t)ch * 57 + (size_t)ri) * 132;
  auto ring_out = [&](int k1, int k2, int slot) {
    int dt = (2 * k1) % r;
    float cb = tw[2 * dt], sbr = tw[2 * dt + 1];
    int dt2 = (2 * dt) % r;
    float cs = tw[2 * dt2], ss = tw[2 * dt2 + 1];
    float ca = 1.f, sa = 0.f;
    float ar = 0.f, ai = 0.f;
    int i = 0;
    for (; i + 1 < c; i += 2) {
      float2 e = P1[i * hp1 + k2];
      ar += e.x * ca + e.y * sa; ai += e.y * ca - e.x * sa;
      float2 e2 = P1[(i + 1) * hp1 + k2];
      ar += e2.x * cb + e2.y * sbr; ai += e2.y * cb - e2.x * sbr;
      ROT(ca, sa, cs, ss); ROT(cb, sbr, cs, ss);
    }
    if (i < c) {
      float2 e = P1[i * hp1 + k2];
      ar += e.x * ca + e.y * sa; ai += e.y * ca - e.x * sa;
    }
    ringp[slot] = make_float2(ar * invcc, ai * invcc);
  };
  if (r == 16) {
    for (int idx = tid; idx < 40; idx += NTT_) ring_out(idx / 5, idx % 5, idx);
  } else {
    int nA = hp1, total = 2 * nA + c;
    for (int idx = tid; idx < total; idx += NTT_) {
      int k1, k2;
      if (idx < nA) { k1 = h; k2 = idx; }
      else if (idx < 2 * nA) { k1 = c - h; k2 = idx - nA; }
      else { k1 = idx - 2 * nA; k2 = h; }
      ring_out(k1, k2, idx);
    }
  }
}

// ---------------------------------------------------------------------------
// Final assembly: out = Hermitian-extension projection of x_out (no FFTs).
// ---------------------------------------------------------------------------
__device__ __forceinline__ float2 loadA(int ch, int k1, int k2) {
  int o = g_owner[k1 * 33 + k2];
  if (o < 0) return make_float2(0.f, 0.f);
  return g_ring[((size_t)ch * 57 + (o >> 8)) * 132 + (o & 255)];
}

__global__ __launch_bounds__(NT) void assemble_kernel(float* __restrict__ out) {
  size_t gid = (size_t)blockIdx.x * NT + threadIdx.x;
  if (gid >= (size_t)NCH * 4096) return;
  int ch = (int)(gid >> 12);
  int rem = (int)(gid & 4095);
  int k1 = rem >> 6, k2f = rem & 63;
  float2 v;
  if (k2f <= 32) {
    float2 a = loadA(ch, k1, k2f);
    if (k2f == 0 || k2f == 32) {
      float2 b = loadA(ch, (64 - k1) & 63, k2f);
      v = make_float2(0.5f * (a.x + b.x), 0.5f * (a.y - b.y));
    } else v = a;
  } else {
    float2 a = loadA(ch, (64 - k1) & 63, 64 - k2f);
    v = make_float2(a.x, -a.y);
  }
  out[2 * gid] = v.x;
  out[2 * gid + 1] = v.y;
}

// ---------------------------------------------------------------------------
static int lds_floats(int r) {
  int c = r >> 1, cp1 = c + 1, c2 = (c >> 1) + 1;
  int base = 2 * r + 2 * c * c2 + 2 * 16 * c2 + 4;
  int kC = (2 * c2 + 31) >> 5;
  int mtE = (c + 15) >> 4;
  int kE = (c + 31) >> 5;
  int newC = kC * 512 + 16 * r + mtE * kE * 512;
  int big;
  if (r == 128) {
    int sba = 8 * r;
    big = newC > sba ? newC : sba;
  } else {
    int KTT = 32 * ((2 * c + 31) >> 5);
    int NTP = 16 * ((cp1 + 15) >> 4);
    int KSY = 2 * NTP;
    int apha = NTP * (KTT + 8) + 16 * (KSY + 8) + 16 * (KTT + 8);
    big = apha > newC ? apha : newC;
  }
  return base + big;
}

extern "C" void kernel_launch(void* const* d_in, const int* in_sizes, int n_in,
                              void* d_out, int out_size, void* d_ws, size_t ws_size,
                              hipStream_t stream) {
  (void)in_sizes; (void)n_in; (void)d_ws; (void)ws_size; (void)out_size;
  const float* x = (const float*)d_in[0];
  float* out = (float*)d_out;

  hipFuncSetAttribute(reinterpret_cast<const void*>(pipe_kernel<NT>),
                      hipFuncAttributeMaxDynamicSharedMemorySize, 160 * 1024);

  hipLaunchKernelGGL(owner_kernel, dim3(9), dim3(NT), 0, stream);
  hipLaunchKernelGGL(wprep_kernel, dim3(57), dim3(256), 0, stream);
  hipLaunchKernelGGL(r1_kernel, dim3(NCH * 8), dim3(NT), 0, stream, x);
  hipLaunchKernelGGL(r2_kernel, dim3(NCH * 9), dim3(NT), 0, stream);

  hipLaunchKernelGGL(pipe_kernel<NT>, dim3(15 * NCH), dim3(NT),
                     (size_t)lds_floats(126) * 4, stream, x, 126); // 98..126
  hipLaunchKernelGGL(pipe_kernel<NT>, dim3(1 * NCH), dim3(NT),
                     (size_t)lds_floats(128) * 4, stream, x, 128); // 128
  hipLaunchKernelGGL(pipe_kernel<NT>, dim3(16 * NCH), dim3(NT),
                     (size_t)lds_floats(96) * 4, stream, x, 96);   // 66..96
  hipLaunchKernelGGL(pipe_kernel<NT>, dim3(16 * NCH), dim3(NT),
                     (size_t)lds_floats(64) * 4, stream, x, 64);   // 34..64
  hipLaunchKernelGGL(pipe_kernel<NT>, dim3(9 * NCH), dim3(NT),
                     (size_t)lds_floats(32) * 4, stream, x, 32);   // 16..32

  hipLaunchKernelGGL(assemble_kernel, dim3((NCH * 4096) / NT), dim3(NT), 0, stream, out);
}

// Round 4
// 12293.259 us; speedup vs baseline: 2.1520x; 1.1458x over previous
//
#include <hip/hip_runtime.h>
#include <math.h>

#define NCH 2048
#define NT 256

typedef _Float16 h8 __attribute__((ext_vector_type(8)));
typedef float f4 __attribute__((ext_vector_type(4)));

#define MFMA(d, a, b) d = __builtin_amdgcn_mfma_f32_16x16x32_f16(a, b, d, 0, 0, 0)

// Static device scratch (avoids any assumption about ws_size).
__device__ float2 g_X[(size_t)NCH * 128 * 65];     // 136 MB
__device__ float2 g_Y[(size_t)NCH * 128 * 65];     // 136 MB
__device__ float2 g_ring[(size_t)NCH * 57 * 132];  // 123 MB
__device__ int    g_owner[64 * 33];
// Stage-A twiddle fragments, fp16 hi/lo (lo pre-scaled x2048).
// Per-res slot = 114688 fp16: [Wtt 8x8192][Wsyn 2x16384][Wana 2x8192]
__device__ _Float16 g_W[(size_t)56 * 114688];      // 12.8 MB
// C/E-phase tables per res (57 slots incl r=128), fp16 offsets:
//   0: WDhi[16384] 16384: WDlo | 32768: Wc2hi[12288] 45056: Wc2lo
//   57344: WEhi[5120] 62464: WElo  (total 67584)
__device__ _Float16 g_W2[(size_t)57 * 67584];      // 7.7 MB
// Per-block TB fragment scratch: [ntB][ktt2][hi 512 | lo 512] fp16
__device__ _Float16 g_TBF[(size_t)32768 * 20480];  // 1.34 GB

__device__ __forceinline__ float gelu_exact(float v) {
  return 0.5f * v * (1.0f + erff(v * 0.70710678118654752440f));
}

// incremental complex rotation: (co,si) *= (cs,ss)
#define ROT(co, si, cs, ss) { float _n = co * cs - si * ss; si = si * cs + co * ss; co = _n; }

// ---------------------------------------------------------------------------
// R1: row-wise DFT along v: Y[ch,u,k2] = sum_v x[ch,u,v] e^{-2pi i k2 v/128}
// ---------------------------------------------------------------------------
__global__ __launch_bounds__(NT) void r1_kernel(const float* __restrict__ x) {
  __shared__ float xb[16 * 128];
  __shared__ float tw[256];
  int ch = blockIdx.x >> 3, grp = blockIdx.x & 7;
  int tid = threadIdx.x;
  for (int t = tid; t < 128; t += NT) {
    float s, co; sincosf(6.283185307179586f * (float)t / 128.0f, &s, &co);
    tw[2 * t] = co; tw[2 * t + 1] = s;
  }
  const float* xp = x + ((size_t)ch * 128 + grp * 16) * 128;
  for (int i = tid; i < 16 * 128; i += NT) xb[i] = xp[i];
  __syncthreads();
  for (int idx = tid; idx < 16 * 65; idx += NT) {
    int u = idx / 65, k2 = idx - 65 * u;
    const float* row = xb + u * 128;
    float cb = tw[2 * k2], sbr = tw[2 * k2 + 1];
    int t2 = (2 * k2) & 127;
    float cs = tw[2 * t2], ss = tw[2 * t2 + 1];
    float ca = 1.f, sa = 0.f;
    float ar = 0.f, ai = 0.f;
    for (int v = 0; v < 128; v += 2) {
      float x0 = row[v], x1 = row[v + 1];
      ar += x0 * ca; ai -= x0 * sa;
      ar += x1 * cb; ai -= x1 * sbr;
      ROT(ca, sa, cs, ss); ROT(cb, sbr, cs, ss);
    }
    g_Y[((size_t)ch * 128 + grp * 16 + u) * 65 + k2] = make_float2(ar, ai);
  }
}

// ---------------------------------------------------------------------------
// R2: col-wise DFT along u + 1/16384 norm. Pairs k1 and k1+64 via (-1)^u.
// ---------------------------------------------------------------------------
__global__ __launch_bounds__(NT) void r2_kernel() {
  __shared__ float2 yb[128 * 8];
  __shared__ float tw[256];
  int ch = blockIdx.x / 9, cg = blockIdx.x - 9 * ch;
  int c0 = cg * 8, nc = min(8, 65 - c0);
  int tid = threadIdx.x;
  for (int t = tid; t < 128; t += NT) {
    float s, co; sincosf(6.283185307179586f * (float)t / 128.0f, &s, &co);
    tw[2 * t] = co; tw[2 * t + 1] = s;
  }
  for (int i = tid; i < 128 * nc; i += NT) {
    int u = i / nc, j = i - nc * u;
    yb[u * 8 + j] = g_Y[((size_t)ch * 128 + u) * 65 + c0 + j];
  }
  __syncthreads();
  const float inv = 1.0f / 16384.0f;
  for (int idx = tid; idx < 64 * nc; idx += NT) {
    int k1 = idx & 63, j = idx >> 6;
    float cb = tw[2 * k1], sbr = tw[2 * k1 + 1];
    int t2 = (2 * k1) & 127;
    float cs = tw[2 * t2], ss = tw[2 * t2 + 1];
    float ca = 1.f, sa = 0.f;
    float ar = 0.f, ai = 0.f, br = 0.f, bi = 0.f;
    for (int u = 0; u < 128; u += 2) {
      float2 e = yb[u * 8 + j];
      float pr = e.x * ca + e.y * sa, pi2 = e.y * ca - e.x * sa;
      ar += pr; ai += pi2; br += pr; bi += pi2;
      e = yb[(u + 1) * 8 + j];
      float pr2 = e.x * cb + e.y * sbr, pi3 = e.y * cb - e.x * sbr;
      ar += pr2; ai += pi3; br -= pr2; bi -= pi3;
      ROT(ca, sa, cs, ss); ROT(cb, sbr, cs, ss);
    }
    g_X[((size_t)ch * 128 + k1) * 65 + c0 + j]      = make_float2(ar * inv, ai * inv);
    g_X[((size_t)ch * 128 + k1 + 64) * 65 + c0 + j] = make_float2(br * inv, bi * inv);
  }
}

// ---------------------------------------------------------------------------
// Owner map (reference's sequential overwrite order).
// ---------------------------------------------------------------------------
__device__ __forceinline__ int owner_slot(int rr, int k2, int ri) {
  if (ri == 0) {
    if (k2 <= 4) {
      if (rr <= 3) return rr * 5 + k2;
      if (rr >= 60) return (rr - 56) * 5 + k2;
    }
    return -1;
  }
  int res = 16 + 2 * ri, c = res / 2, h = c / 2;
  if (c & 1) {
    if (rr == h && k2 <= h) return k2;
    if (rr == 64 - h && k2 <= h) return (h + 1) + k2;
    if (k2 == h) {
      if (rr <= h) return 2 * (h + 1) + rr;
      if (rr >= 64 - h) return 2 * (h + 1) + (rr - 64 + c);
    }
  } else {
    if (rr == 64 - h && k2 <= h) return (h + 1) + k2;
    if (k2 == h) {
      if (rr >= 64 - h) return 2 * (h + 1) + (rr - 64 + c);
      if (rr < h) return 2 * (h + 1) + rr;
    }
  }
  return -1;
}

__global__ __launch_bounds__(NT) void owner_kernel() {
  int cell = blockIdx.x * NT + threadIdx.x;
  if (cell >= 64 * 33) return;
  int rr = cell / 33, k2 = cell - 33 * (cell / 33);
  int result = -1;
  for (int ri = 56; ri >= 0 && result < 0; ri--) {
    int slot = owner_slot(rr, k2, ri);
    if (slot >= 0) result = ri * 256 + slot;
  }
  g_owner[cell] = result;
}

// ---------------------------------------------------------------------------
// Twiddle-fragment precompute, r = 16..128 step 2 (ri = (r-16)/2).
// Fragment packing (16x32 tile = 512 fp16): value(row/col = l&15,
// k = (l>>4)*8 + e).  hi/lo split: lo = (v - (f32)(f16)v) * 2048.
// ---------------------------------------------------------------------------
__global__ __launch_bounds__(256) void wprep_kernel() {
  int r = 16 + 2 * blockIdx.x;
  int c = r >> 1, cp1 = c + 1, c2 = (c >> 1) + 1;
  const float TP = 6.283185307179586f;
  const float PIF_ = 3.14159265358979f;
  float invr = 1.0f / (float)r;

  if (r <= 126) {
    int KTT = 32 * ((2 * c + 31) >> 5);
    int NTP = 16 * ((cp1 + 15) >> 4);
    int KSY = 2 * NTP;
    int NSY = KTT;
    int NAN_ = 16 * ((2 * c2 + 15) >> 4);
    int MT = (c + 15) >> 4;
    int ktt = KTT >> 5, kts = KSY >> 5;
    _Float16* W = g_W + (size_t)blockIdx.x * 114688;

    // ---- Wtt: s = par*4 + v*2 + h.  A1=(cos,-sin) -> re, A2=(sin,cos) -> im
    int tot = 8 * MT * ktt * 64;
    for (int fi = threadIdx.x; fi < tot; fi += 256) {
      int l = fi & 63, rest = fi >> 6;
      int kt = rest % ktt; rest /= ktt;
      int mt = rest % MT;  rest /= MT;
      int s = rest;
      int hh = s & 1, vv = (s >> 1) & 1, par = s >> 2;
      int i = mt * 16 + (l & 15);
      int u = 2 * i + par;
      int kb = kt * 32 + (l >> 4) * 8;
      h8 o;
      for (int e = 0; e < 8; e++) {
        int k = kb + e, kk = k >> 1, im = k & 1;
        float val = 0.f;
        if (i < c && kk < c) {
          int tm = (u * kk) % r;
          float sn, cs; sincosf(TP * (float)tm * invr, &sn, &cs);
          val = (vv == 0) ? (im ? -sn : cs) : (im ? cs : sn);
        }
        if (hh) { float hi = (float)(_Float16)val; val = (val - hi) * 2048.f; }
        o[e] = (_Float16)val;
      }
      *(h8*)(W + s * 8192 + (mt * ktt + kt) * 512 + l * 8) = o;
    }
    // ---- Wsyn (B-type): k-interleave (2k2)=alpha*cos, (2k2+1)=-alpha*sin
    int nts = NSY >> 4;
    tot = 2 * nts * kts * 64;
    for (int fi = threadIdx.x; fi < tot; fi += 256) {
      int l = fi & 63, rest = fi >> 6;
      int kt = rest % kts; rest /= kts;
      int nt = rest % nts; rest /= nts;
      int hh = rest;
      int v = nt * 16 + (l & 15);
      int kb = kt * 32 + (l >> 4) * 8;
      h8 o;
      for (int e = 0; e < 8; e++) {
        int k = kb + e, k2 = k >> 1, im = k & 1;
        float val = 0.f;
        if (k2 <= c) {
          int tm = (v * k2) % r;
          if (im) {
            if (k2 != 0 && k2 != c) val = -2.f * sinf(TP * (float)tm * invr);
          } else {
            float a = (k2 == 0 || k2 == c) ? 1.f : 2.f;
            val = a * cosf(TP * (float)tm * invr);
          }
        }
        if (hh) { float hi = (float)(_Float16)val; val = (val - hi) * 2048.f; }
        o[e] = (_Float16)val;
      }
      *(h8*)(W + 65536 + hh * 16384 + (nt * kts + kt) * 512 + l * 8) = o;
    }
    // ---- Wana (B-type): col n: even->cos(2pi k2 v/r), odd->-sin; k dim = v
    int nta = NAN_ >> 4;
    tot = 2 * nta * ktt * 64;
    for (int fi = threadIdx.x; fi < tot; fi += 256) {
      int l = fi & 63, rest = fi >> 6;
      int kt = rest % ktt; rest /= ktt;
      int nt = rest % nta; rest /= nta;
      int hh = rest;
      int n = nt * 16 + (l & 15);
      int k2 = n >> 1, im = n & 1;
      int kb = kt * 32 + (l >> 4) * 8;
      h8 o;
      for (int e = 0; e < 8; e++) {
        int v = kb + e;
        float val = 0.f;
        if (n < 2 * c2 && v < r) {
          int tm = (k2 * v) % r;
          val = im ? -sinf(TP * (float)tm * invr) : cosf(TP * (float)tm * invr);
        }
        if (hh) { float hi = (float)(_Float16)val; val = (val - hi) * 2048.f; }
        o[e] = (_Float16)val;
      }
      *(h8*)(W + 98304 + hh * 8192 + (nt * ktt + kt) * 512 + l * 8) = o;
    }
  }

  // ---- C/E-phase tables in g_W2 ----
  _Float16* W2 = g_W2 + (size_t)blockIdx.x * 67584;
  int mtD = (r + 15) >> 4, ktD = (r + 31) >> 5;
  {
    // WD (A-type): Dirichlet K(u'-u) * 64/r^2.  K(0)=c, else sin(pi c d/r)/sin(pi d/r)
    float sK = 64.0f / ((float)r * (float)r);
    int tot = 2 * mtD * ktD * 64;
    for (int fi = threadIdx.x; fi < tot; fi += 256) {
      int l = fi & 63, rest = fi >> 6;
      int kt = rest % ktD; rest /= ktD;
      int mt = rest % mtD; rest /= mtD;
      int hh = rest;
      int up = mt * 16 + (l & 15);
      int kb = kt * 32 + (l >> 4) * 8;
      h8 o;
      for (int e = 0; e < 8; e++) {
        int u = kb + e;
        float val = 0.f;
        if (up < r && u < r) {
          int d = up - u;
          if (d == 0) val = (float)c * sK;
          else {
            int nm = (c * d) % (2 * r);
            val = sinf(PIF_ * (float)nm * invr) / sinf(PIF_ * (float)d * invr) * sK;
          }
        }
        if (hh) { float hi = (float)(_Float16)val; val = (val - hi) * 2048.f; }
        o[e] = (_Float16)val;
      }
      *(h8*)(W2 + hh * 16384 + (mt * ktD + kt) * 512 + l * 8) = o;
    }
  }
  {
    // Wc2 (B-type): col v, k=2k2+im: [2k2]=alpha*cos(2pi v k2/r), [2k2+1]=-alpha*sin
    int ntC = mtD, kC = (2 * c2 + 31) >> 5;
    int tot = 2 * ntC * kC * 64;
    for (int fi = threadIdx.x; fi < tot; fi += 256) {
      int l = fi & 63, rest = fi >> 6;
      int kt = rest % kC; rest /= kC;
      int nt = rest % ntC; rest /= ntC;
      int hh = rest;
      int v = nt * 16 + (l & 15);
      int kb = kt * 32 + (l >> 4) * 8;
      h8 o;
      for (int e = 0; e < 8; e++) {
        int k = kb + e, k2 = k >> 1, im = k & 1;
        float val = 0.f;
        if (v < r && k2 < c2) {
          float al = (k2 == 0) ? 1.f : 2.f;
          int tm = (v * k2) % r;
          val = im ? -al * sinf(TP * (float)tm * invr) : al * cosf(TP * (float)tm * invr);
        }
        if (hh) { float hi = (float)(_Float16)val; val = (val - hi) * 2048.f; }
        o[e] = (_Float16)val;
      }
      *(h8*)(W2 + 32768 + hh * 12288 + (nt * kC + kt) * 512 + l * 8) = o;
    }
  }
  {
    // WE (B-type): col n=2k2+im, k=v: cos(2pi k2 v/c) / -sin
    int hq = c >> 1;
    int ntE = (2 * (hq + 1) + 15) >> 4, kE = (c + 31) >> 5;
    float invc = 1.0f / (float)c;
    int tot = 2 * ntE * kE * 64;
    for (int fi = threadIdx.x; fi < tot; fi += 256) {
      int l = fi & 63, rest = fi >> 6;
      int kt = rest % kE; rest /= kE;
      int nt = rest % ntE; rest /= ntE;
      int hh = rest;
      int n = nt * 16 + (l & 15);
      int k2 = n >> 1, im = n & 1;
      int kb = kt * 32 + (l >> 4) * 8;
      h8 o;
      for (int e = 0; e < 8; e++) {
        int v = kb + e;
        float val = 0.f;
        if (n < 2 * (hq + 1) && v < c) {
          int tm = (k2 * v) % c;
          val = im ? -sinf(TP * (float)tm * invc) : cosf(TP * (float)tm * invc);
        }
        if (hh) { float hi = (float)(_Float16)val; val = (val - hi) * 2048.f; }
        o[e] = (_Float16)val;
      }
      *(h8*)(W2 + 57344 + hh * 5120 + (nt * kE + kt) * 512 + l * 8) = o;
    }
  }
}

// ---------------------------------------------------------------------------
// Per-(channel,res) pipeline.  Stage A: TTmm -> syn+gelu -> ana (MFMA), ana
// writes phase-rotated TB fragments to global TBF (all slots -> no zero-init
// needed for r<=126; MT == ktt2 guarantees full u coverage).  C-phase:
// Dirichlet matmul, C2 synthesis, maxpool, pooled-DFT, ring outputs.
// ---------------------------------------------------------------------------
template <int NTT_>
__global__ __launch_bounds__(NTT_) void pipe_kernel(const float* __restrict__ x, int res_hi) {
  const int NU = 8;
  int rorder = blockIdx.x / NCH;
  int ch = blockIdx.x - rorder * NCH;
  int r = res_hi - 2 * rorder;
  const int tid = threadIdx.x;
  const int lane = tid & 63;
  const int wid = tid >> 6;
  const int l15 = lane & 15;
  const int lk = (lane >> 4) << 3;
  int c = r >> 1, cp1 = c + 1, c2 = (c >> 1) + 1, h = c >> 1;
  bool is128 = (r == 128);
  int ri = (r - 16) >> 1;

  const int ktt2 = (r + 31) >> 5;       // TBF K-tiles (K = u over r)
  const int ntB  = (2 * c2 + 15) >> 4;  // TBF / ana n-tiles
  const int mtD  = (r + 15) >> 4;       // u'-tiles
  const int kC   = (2 * c2 + 31) >> 5;  // C2 K-tiles
  const int mtE  = (c + 15) >> 4;
  const int kE   = (c + 31) >> 5;
  const bool srotOn = ((c & 1) == 0);   // sigma rotation only for c even
  const float LSC = 4.8828125e-4f;      // 1/2048

  extern __shared__ float lds[];
  float* tw = lds;                      // 2r: cos/sin(2pi t/r)
  float* tw2 = lds + 2 * r;             // 2r: cos/sin(pi t/r)
  float* gdp = lds + 4 * r;             // P1 overlay region (2*c*c2 floats)
  float* tbp = gdp + 2 * c * c2;        // TB f32 (128-path) 2*16*c2
  float2* TB = (float2*)tbp;
  float* big = (float*)(((size_t)(tbp + 2 * 16 * c2) + 15) & ~(size_t)15);

  _Float16* tbf = g_TBF + (size_t)blockIdx.x * 20480;
  if (is128) {
    // only the 128 path needs zero-init (its VALU ana covers only n < 2*c2)
    f4 z = {0.f, 0.f, 0.f, 0.f};
    int ntot = ntB * ktt2 * 128;
    for (int i = tid; i < ntot; i += NTT_) *(f4*)(tbf + i * 8) = z;
  }

  for (int t = tid; t < r; t += NTT_) {
    float s, co;
    sincosf(6.283185307179586f * (float)t / (float)r, &s, &co);
    tw[2 * t] = co; tw[2 * t + 1] = s;
    sincosf(3.14159265358979f * (float)t / (float)r, &s, &co);
    tw2[2 * t] = co; tw2[2 * t + 1] = s;
  }
  __syncthreads();

  const float2* Xc = g_X + (size_t)ch * (128 * 65);

  if (!is128) {
    const int KTT = 32 * ((2 * c + 31) >> 5);
    const int NTP = 16 * ((cp1 + 15) >> 4);
    const int KSY = 2 * NTP;
    const int NSY = KTT;
    const int MT = (c + 15) >> 4;       // == ktt2
    const int ktt = KTT >> 5, kts = KSY >> 5;
    const int sA = KTT + 8, sT = KSY + 8;
    const _Float16* Wslot = g_W + (size_t)ri * 114688;
    const _Float16* Wsy = Wslot + 65536;
    const _Float16* Wan = Wslot + 98304;
    _Float16* feHI = (_Float16*)big;
    _Float16* feLO = feHI + NTP * sA;
    _Float16* ttHI = feLO + NTP * sA;
    _Float16* ttLO = ttHI + 16 * sT;
    _Float16* sbHI = ttLO + 16 * sT;
    _Float16* sbLO = sbHI + 16 * sA;
    const int halfK = KTT >> 1;

    for (int par = 0; par < 2; par++) {
      // ---- folded crop fe = pa +/- pb, transposed [j][2kk], hi/lo
      {
        int total = NTP * halfK;
        int j = tid % NTP, kk = tid / NTP;
        const int jS = NTT_ % NTP, kS = NTT_ / NTP;
        for (int idx = tid; idx < total; idx += NTT_) {
          float fx = 0.f, fy = 0.f;
          if (j < cp1 && kk < c) {
            float2 e1 = Xc[(size_t)kk * 65 + j];
            float2 e2 = Xc[(size_t)(128 - c + kk) * 65 + j];
            fx = par ? (e1.x - e2.x) : (e1.x + e2.x);
            fy = par ? (e1.y - e2.y) : (e1.y + e2.y);
          }
          int base = j * sA + 2 * kk;
          _Float16 xh = (_Float16)fx, yh = (_Float16)fy;
          feHI[base] = xh; feHI[base + 1] = yh;
          feLO[base] = (_Float16)((fx - (float)xh) * 2048.f);
          feLO[base + 1] = (_Float16)((fy - (float)yh) * 2048.f);
          j += jS; kk += kS; if (j >= NTP) { j -= NTP; kk++; }
        }
      }
      __syncthreads();

      for (int p = 0; p < MT; p++) {
        // ---- TTmm
        for (int nt = wid; nt < (NTP >> 4); nt += NTT_ / 64) {
          f4 d1r = {0.f, 0.f, 0.f, 0.f}, d2r = d1r, d1i = d1r, d2i = d1r;
          const _Float16* pa1h = Wslot + (par * 4 + 0) * 8192 + (p * ktt) * 512 + lane * 8;
          const _Float16* pa1l = pa1h + 8192;
          const _Float16* pa2h = pa1h + 16384;
          const _Float16* pa2l = pa1h + 24576;
          const _Float16* pbh = feHI + (nt * 16 + l15) * sA + lk;
          const _Float16* pbl = feLO + (nt * 16 + l15) * sA + lk;
          for (int kt = 0; kt < ktt; kt++) {
            h8 A1h = *(const h8*)(pa1h + kt * 512);
            h8 A1l = *(const h8*)(pa1l + kt * 512);
            h8 A2h = *(const h8*)(pa2h + kt * 512);
            h8 A2l = *(const h8*)(pa2l + kt * 512);
            h8 Bh = *(const h8*)(pbh + kt * 32);
            h8 Bl = *(const h8*)(pbl + kt * 32);
            MFMA(d1r, A1h, Bh);
            MFMA(d2r, A1l, Bh); MFMA(d2r, A1h, Bl);
            MFMA(d1i, A2h, Bh);
            MFMA(d2i, A2l, Bh); MFMA(d2i, A2h, Bl);
          }
          int j = nt * 16 + l15;
          bool jv = j < cp1;
          for (int q = 0; q < 4; q++) {
            int row = (lane >> 4) * 4 + q;
            float re = jv ? (d1r[q] + d2r[q] * LSC) : 0.f;
            float im = jv ? (d1i[q] + d2i[q] * LSC) : 0.f;
            int base = row * sT + 2 * j;
            _Float16 rh = (_Float16)re, ih = (_Float16)im;
            ttHI[base] = rh; ttHI[base + 1] = ih;
            ttLO[base] = (_Float16)((re - (float)rh) * 2048.f);
            ttLO[base + 1] = (_Float16)((im - (float)ih) * 2048.f);
          }
        }
        __syncthreads();
        // ---- syn + gelu
        for (int nt = wid; nt < (NSY >> 4); nt += NTT_ / 64) {
          f4 d1 = {0.f, 0.f, 0.f, 0.f}, d2 = d1;
          const _Float16* pah = ttHI + l15 * sT + lk;
          const _Float16* pal = ttLO + l15 * sT + lk;
          const _Float16* pbh = Wsy + (nt * kts) * 512 + lane * 8;
          const _Float16* pbl = pbh + 16384;
          for (int kt = 0; kt < kts; kt++) {
            h8 Ah = *(const h8*)(pah + kt * 32);
            h8 Al = *(const h8*)(pal + kt * 32);
            h8 Bh = *(const h8*)(pbh + kt * 512);
            h8 Bl = *(const h8*)(pbl + kt * 512);
            MFMA(d1, Ah, Bh);
            MFMA(d2, Al, Bh); MFMA(d2, Ah, Bl);
          }
          int v = nt * 16 + l15;
          bool vv = v < 2 * c;
          for (int q = 0; q < 4; q++) {
            int row = (lane >> 4) * 4 + q;
            float val = vv ? gelu_exact(d1[q] + d2[q] * LSC) : 0.f;
            _Float16 vh = (_Float16)val;
            sbHI[row * sA + v] = vh;
            sbLO[row * sA + v] = (_Float16)((val - (float)vh) * 2048.f);
          }
        }
        __syncthreads();
        // ---- ana -> TBF fragments (sigma rotation via tw2; writes ALL slots)
        for (int nt = wid; nt < ntB; nt += NTT_ / 64) {
          f4 d1 = {0.f, 0.f, 0.f, 0.f}, d2 = d1;
          const _Float16* pah = sbHI + l15 * sA + lk;
          const _Float16* pal = sbLO + l15 * sA + lk;
          const _Float16* pbh = Wan + (nt * ktt) * 512 + lane * 8;
          const _Float16* pbl = pbh + 8192;
          for (int kt = 0; kt < ktt; kt++) {
            h8 Ah = *(const h8*)(pah + kt * 32);
            h8 Al = *(const h8*)(pal + kt * 32);
            h8 Bh = *(const h8*)(pbh + kt * 512);
            h8 Bl = *(const h8*)(pbl + kt * 512);
            MFMA(d1, Ah, Bh);
            MFMA(d2, Al, Bh); MFMA(d2, Ah, Bl);
          }
          int n = nt * 16 + l15;
          for (int q = 0; q < 4; q++) {
            float val = d1[q] + d2[q] * LSC;
            float out = val;
            int row = (lane >> 4) * 4 + q;
            int u = 32 * p + par + 2 * row;
            if (srotOn) {
              float pr = __shfl_xor(val, 1);
              int uc = (u < r) ? u : (r - 1);   // padded rows are zero anyway
              float cf = tw2[2 * uc], sf = tw2[2 * uc + 1];
              out = val * cf + ((n & 1) ? pr * sf : -pr * sf);
            }
            int kin = u & 31;
            int pos = ((n >> 4) * ktt2 + (u >> 5)) * 1024 + ((n & 15) + 16 * (kin >> 3)) * 8 + (kin & 7);
            _Float16 vh = (_Float16)out;
            tbf[pos] = vh;
            tbf[pos + 512] = (_Float16)((out - (float)vh) * 2048.f);
          }
        }
        __syncthreads();
      }
    }
  } else {
    // ---- r == 128: identity stage A (VALU analysis) -> TBF
    const float* xc = x + (size_t)ch * 128 * 128;
    float* SBa = big;
    auto do_analysis = [&](int ns) {
      for (int idx = tid; idx < ns * c2; idx += NTT_) {
        int k2 = idx % c2, i = idx / c2;
        const float* gp = SBa + i * r;
        float sk2 = (k2 & 1) ? -1.f : 1.f;
        float cb = tw[2 * k2], sbr = tw[2 * k2 + 1];
        int t2 = (2 * k2) % r;
        float cs = tw[2 * t2], ss = tw[2 * t2 + 1];
        float ca = 1.f, sa = 0.f;
        float ar = 0.f, ai = 0.f;
        int v = 0;
        for (; v + 1 < c; v += 2) {
          float f1 = fmaf(sk2, gp[v + c], gp[v]);
          ar += f1 * ca; ai -= f1 * sa;
          float f2 = fmaf(sk2, gp[v + 1 + c], gp[v + 1]);
          ar += f2 * cb; ai -= f2 * sbr;
          ROT(ca, sa, cs, ss); ROT(cb, sbr, cs, ss);
        }
        if (v < c) {
          float f1 = fmaf(sk2, gp[v + c], gp[v]);
          ar += f1 * ca; ai -= f1 * sa;
        }
        TB[idx] = make_float2(ar, ai);
      }
    };
    for (int ub = 0; ub < r; ub += NU) {
      for (int idx = tid; idx < NU * r; idx += NTT_) {
        int v = idx & 127, i = idx >> 7;
        SBa[i * r + v] = gelu_exact(xc[(ub + i) * 128 + v]);
      }
      __syncthreads();
      do_analysis(NU);
      __syncthreads();
      for (int idx = tid; idx < NU * c2; idx += NTT_) {
        int k2 = idx % c2, i = idx / c2;
        float2 e = TB[i * c2 + k2];
        int u = ub + i;
        float cf = tw2[2 * u], sf = tw2[2 * u + 1];
        float re = e.x * cf - e.y * sf;
        float im_ = e.x * sf + e.y * cf;
        int kin = u & 31, kt = u >> 5;
        int n0 = 2 * k2;
        int pos0 = ((n0 >> 4) * ktt2 + kt) * 1024 + ((n0 & 15) + 16 * (kin >> 3)) * 8 + (kin & 7);
        _Float16 vh = (_Float16)re;
        tbf[pos0] = vh; tbf[pos0 + 512] = (_Float16)((re - (float)vh) * 2048.f);
        int n1 = n0 + 1;
        int pos1 = ((n1 >> 4) * ktt2 + kt) * 1024 + ((n1 & 15) + 16 * (kin >> 3)) * 8 + (kin & 7);
        vh = (_Float16)im_;
        tbf[pos1] = vh; tbf[pos1 + 512] = (_Float16)((im_ - (float)vh) * 2048.f);
      }
      __syncthreads();
    }
  }

  // ---- C-phase: per u'-tile: Dirichlet matmul -> T, synthesis -> S, maxpool
  _Float16* tAhi = (_Float16*)big;
  _Float16* tAlo = tAhi + kC * 512;
  float* Sf = big + kC * 512;
  float* paf = Sf + 16 * r;
  _Float16* pAhi = (_Float16*)paf;
  _Float16* pAlo = pAhi + mtE * kE * 512;
  for (int i = tid; i < kC * 512; i += NTT_) ((float*)tAhi)[i] = 0.f;
  for (int i = tid; i < mtE * kE * 512; i += NTT_) paf[i] = 0.f;
  __syncthreads();

  const _Float16* WDhi = g_W2 + (size_t)ri * 67584;
  const _Float16* WDlo = WDhi + 16384;
  const _Float16* Wc2hi = WDhi + 32768;
  const _Float16* Wc2lo = WDhi + 45056;
  const _Float16* WEhi = WDhi + 57344;
  const _Float16* WElo = WDhi + 62464;

  const int mjS = NTT_ % c, miS = NTT_ / c;
  const int jj0 = tid % c, i20 = tid / c;
  for (int mt = 0; mt < mtD; mt++) {
    // Dirichlet (real K) matmul: T[mt*16+ul][n], unscale 1/64, rotate, -> tA
    for (int nt = wid; nt < ntB; nt += NTT_ / 64) {
      f4 d1 = {0.f, 0.f, 0.f, 0.f}, d2 = d1;
      const _Float16* pah = WDhi + (mt * ktt2) * 512 + lane * 8;
      const _Float16* pal = WDlo + (mt * ktt2) * 512 + lane * 8;
      const _Float16* pbb = tbf + (nt * ktt2) * 1024 + lane * 8;
      for (int kt = 0; kt < ktt2; kt++) {
        h8 Ah = *(const h8*)(pah + kt * 512);
        h8 Al = *(const h8*)(pal + kt * 512);
        h8 Bh = *(const h8*)(pbb + kt * 1024);
        h8 Bl = *(const h8*)(pbb + kt * 1024 + 512);
        MFMA(d1, Ah, Bh); MFMA(d2, Al, Bh); MFMA(d2, Ah, Bl);
      }
      int n = nt * 16 + l15;
      for (int q = 0; q < 4; q++) {
        float val = (d1[q] + d2[q] * LSC) * 0.015625f;
        float out = val;
        int ul = (lane >> 4) * 4 + q;
        if (srotOn) {
          float pr = __shfl_xor(val, 1);
          int up = mt * 16 + ul;
          if (up >= r) up = r - 1;        // pad rows are zero anyway
          float cf = tw2[2 * up], sf = -tw2[2 * up + 1];
          out = val * cf + ((n & 1) ? pr * sf : -pr * sf);
        }
        if (n < 2 * c2) {
          int pos = (n >> 5) * 512 + (ul + 16 * ((n & 31) >> 3)) * 8 + (n & 7);
          _Float16 vh = (_Float16)out;
          tAhi[pos] = vh;
          tAlo[pos] = (_Float16)((out - (float)vh) * 2048.f);
        }
      }
    }
    __syncthreads();
    // row synthesis: S[ul][v]
    for (int nt = wid; nt < mtD; nt += NTT_ / 64) {
      f4 d1 = {0.f, 0.f, 0.f, 0.f}, d2 = d1;
      for (int kt = 0; kt < kC; kt++) {
        h8 Ah = *(const h8*)(tAhi + kt * 512 + lane * 8);
        h8 Al = *(const h8*)(tAlo + kt * 512 + lane * 8);
        h8 Bh = *(const h8*)(Wc2hi + (nt * kC + kt) * 512 + lane * 8);
        h8 Bl = *(const h8*)(Wc2lo + (nt * kC + kt) * 512 + lane * 8);
        MFMA(d1, Ah, Bh); MFMA(d2, Al, Bh); MFMA(d2, Ah, Bl);
      }
      int v = nt * 16 + l15;
      if (v < r) {
        for (int q = 0; q < 4; q++) {
          int ul = (lane >> 4) * 4 + q;
          Sf[ul * r + v] = d1[q] + d2[q] * LSC;
        }
      }
    }
    __syncthreads();
    // 2x2 maxpool -> P A-fragments
    {
      int jj = jj0, i2 = i20;
      for (int idx = tid; idx < 8 * c; idx += NTT_) {
        const float* s0p = Sf + (2 * i2) * r;
        const float* s1p = Sf + (2 * i2 + 1) * r;
        float pv = fmaxf(fmaxf(s0p[2 * jj], s0p[2 * jj + 1]),
                         fmaxf(s1p[2 * jj], s1p[2 * jj + 1]));
        int i = mt * 8 + i2;
        int pos = ((i >> 4) * kE + (jj >> 5)) * 512 + ((i & 15) + 16 * ((jj & 31) >> 3)) * 8 + (jj & 7);
        _Float16 vh = (_Float16)pv;
        pAhi[pos] = vh;
        pAlo[pos] = (_Float16)((pv - (float)vh) * 2048.f);
        jj += mjS; i2 += miS; if (jj >= c) { jj -= c; i2++; }
      }
    }
    __syncthreads();
  }

  // ---- E: pooled-image row DFT (MFMA) -> P1 (overlays gdp)
  int ntE = ntB;
  for (int t2 = wid; t2 < mtE * ntE; t2 += NTT_ / 64) {
    int mt = t2 / ntE, nt = t2 - mt * ntE;
    f4 d1 = {0.f, 0.f, 0.f, 0.f}, d2 = d1;
    for (int kt = 0; kt < kE; kt++) {
      h8 Ah = *(const h8*)(pAhi + (mt * kE + kt) * 512 + lane * 8);
      h8 Al = *(const h8*)(pAlo + (mt * kE + kt) * 512 + lane * 8);
      h8 Bh = *(const h8*)(WEhi + (nt * kE + kt) * 512 + lane * 8);
      h8 Bl = *(const h8*)(WElo + (nt * kE + kt) * 512 + lane * 8);
      MFMA(d1, Ah, Bh); MFMA(d2, Al, Bh); MFMA(d2, Ah, Bl);
    }
    int n = nt * 16 + l15;
    if (n < 2 * c2) {
      for (int q = 0; q < 4; q++) {
        int i = mt * 16 + (lane >> 4) * 4 + q;
        if (i < c) gdp[(i * c2 + (n >> 1)) * 2 + (n & 1)] = d1[q] + d2[q] * LSC;
      }
    }
  }
  __syncthreads();

  // ---- ring outputs (VALU, tiny)
  float2* P1 = (float2*)gdp;
  int hp1 = h + 1;
  float invcc = 1.0f / ((float)c * (float)c);
  float2* ringp = g_ring + ((size_t)ch * 57 + (size_t)ri) * 132;
  auto ring_out = [&](int k1, int k2, int slot) {
    int dt = (2 * k1) % r;
    float cb = tw[2 * dt], sbr = tw[2 * dt + 1];
    int dt2 = (2 * dt) % r;
    float cs = tw[2 * dt2], ss = tw[2 * dt2 + 1];
    float ca = 1.f, sa = 0.f;
    float ar = 0.f, ai = 0.f;
    int i = 0;
    for (; i + 1 < c; i += 2) {
      float2 e = P1[i * hp1 + k2];
      ar += e.x * ca + e.y * sa; ai += e.y * ca - e.x * sa;
      float2 e2 = P1[(i + 1) * hp1 + k2];
      ar += e2.x * cb + e2.y * sbr; ai += e2.y * cb - e2.x * sbr;
      ROT(ca, sa, cs, ss); ROT(cb, sbr, cs, ss);
    }
    if (i < c) {
      float2 e = P1[i * hp1 + k2];
      ar += e.x * ca + e.y * sa; ai += e.y * ca - e.x * sa;
    }
    ringp[slot] = make_float2(ar * invcc, ai * invcc);
  };
  if (r == 16) {
    for (int idx = tid; idx < 40; idx += NTT_) ring_out(idx / 5, idx % 5, idx);
  } else {
    int nA = hp1, total = 2 * nA + c;
    for (int idx = tid; idx < total; idx += NTT_) {
      int k1, k2;
      if (idx < nA) { k1 = h; k2 = idx; }
      else if (idx < 2 * nA) { k1 = c - h; k2 = idx - nA; }
      else { k1 = idx - 2 * nA; k2 = h; }
      ring_out(k1, k2, idx);
    }
  }
}

// ---------------------------------------------------------------------------
// Final assembly: out = Hermitian-extension projection of x_out (no FFTs).
// ---------------------------------------------------------------------------
__device__ __forceinline__ float2 loadA(int ch, int k1, int k2) {
  int o = g_owner[k1 * 33 + k2];
  if (o < 0) return make_float2(0.f, 0.f);
  return g_ring[((size_t)ch * 57 + (o >> 8)) * 132 + (o & 255)];
}

__global__ __launch_bounds__(NT) void assemble_kernel(float* __restrict__ out) {
  size_t gid = (size_t)blockIdx.x * NT + threadIdx.x;
  if (gid >= (size_t)NCH * 4096) return;
  int ch = (int)(gid >> 12);
  int rem = (int)(gid & 4095);
  int k1 = rem >> 6, k2f = rem & 63;
  float2 v;
  if (k2f <= 32) {
    float2 a = loadA(ch, k1, k2f);
    if (k2f == 0 || k2f == 32) {
      float2 b = loadA(ch, (64 - k1) & 63, k2f);
      v = make_float2(0.5f * (a.x + b.x), 0.5f * (a.y - b.y));
    } else v = a;
  } else {
    float2 a = loadA(ch, (64 - k1) & 63, 64 - k2f);
    v = make_float2(a.x, -a.y);
  }
  out[2 * gid] = v.x;
  out[2 * gid + 1] = v.y;
}

// ---------------------------------------------------------------------------
static int lds_floats(int r) {
  int c = r >> 1, cp1 = c + 1, c2 = (c >> 1) + 1;
  int base = 4 * r + 2 * c * c2 + 2 * 16 * c2 + 4;
  int kC = (2 * c2 + 31) >> 5;
  int mtE = (c + 15) >> 4;
  int kE = (c + 31) >> 5;
  int newC = kC * 512 + 16 * r + mtE * kE * 512;
  int big;
  if (r == 128) {
    int sba = 8 * r;
    big = newC > sba ? newC : sba;
  } else {
    int KTT = 32 * ((2 * c + 31) >> 5);
    int NTP = 16 * ((cp1 + 15) >> 4);
    int KSY = 2 * NTP;
    int apha = NTP * (KTT + 8) + 16 * (KSY + 8) + 16 * (KTT + 8);
    big = apha > newC ? apha : newC;
  }
  return base + big;
}

extern "C" void kernel_launch(void* const* d_in, const int* in_sizes, int n_in,
                              void* d_out, int out_size, void* d_ws, size_t ws_size,
                              hipStream_t stream) {
  (void)in_sizes; (void)n_in; (void)d_ws; (void)ws_size; (void)out_size;
  const float* x = (const float*)d_in[0];
  float* out = (float*)d_out;

  hipFuncSetAttribute(reinterpret_cast<const void*>(pipe_kernel<NT>),
                      hipFuncAttributeMaxDynamicSharedMemorySize, 160 * 1024);

  hipLaunchKernelGGL(owner_kernel, dim3(9), dim3(NT), 0, stream);
  hipLaunchKernelGGL(wprep_kernel, dim3(57), dim3(256), 0, stream);
  hipLaunchKernelGGL(r1_kernel, dim3(NCH * 8), dim3(NT), 0, stream, x);
  hipLaunchKernelGGL(r2_kernel, dim3(NCH * 9), dim3(NT), 0, stream);

  hipLaunchKernelGGL(pipe_kernel<NT>, dim3(16 * NCH), dim3(NT),
                     (size_t)lds_floats(126) * 4, stream, x, 126); // 96..126 (2 blk/CU)
  hipLaunchKernelGGL(pipe_kernel<NT>, dim3(1 * NCH), dim3(NT),
                     (size_t)lds_floats(128) * 4, stream, x, 128); // 128
  hipLaunchKernelGGL(pipe_kernel<NT>, dim3(15 * NCH), dim3(NT),
                     (size_t)lds_floats(94) * 4, stream, x, 94);   // 66..94 (3 blk/CU)
  hipLaunchKernelGGL(pipe_kernel<NT>, dim3(16 * NCH), dim3(NT),
                     (size_t)lds_floats(64) * 4, stream, x, 64);   // 34..64 (4 blk/CU)
  hipLaunchKernelGGL(pipe_kernel<NT>, dim3(9 * NCH), dim3(NT),
                     (size_t)lds_floats(32) * 4, stream, x, 32);   // 16..32 (8 blk/CU)

  hipLaunchKernelGGL(assemble_kernel, dim3((NCH * 4096) / NT), dim3(NT), 0, stream, out);
}